// Round 8
// baseline (852.221 us; speedup 1.0000x reference)
//
#include <hip/hip_runtime.h>
#include <hip/hip_bf16.h>

using bf16 = __hip_bfloat16;
typedef __bf16 bf16x8 __attribute__((ext_vector_type(8)));
typedef float f32x4 __attribute__((ext_vector_type(4)));

// Sizes (fixed): B=8 S=32 N=64 F_NODE=32 TRI=2016 DIN=2048 H=4 DOUT=256 R=1024
// OUT=2016, G=B*S=256 graphs

__device__ __forceinline__ void unp2(unsigned int u, float& a, float& b) {
  a = __uint_as_float(u << 16);
  b = __uint_as_float(u & 0xffff0000u);
}

__device__ __forceinline__ bf16x8 cvt8(float4 a, float4 b) {
  bf16x8 r;
  r[0] = (__bf16)a.x; r[1] = (__bf16)a.y; r[2] = (__bf16)a.z; r[3] = (__bf16)a.w;
  r[4] = (__bf16)b.x; r[5] = (__bf16)b.y; r[6] = (__bf16)b.z; r[7] = (__bf16)b.w;
  return r;
}

__device__ __forceinline__ float ald(const float* p) {
  return __hip_atomic_load(p, __ATOMIC_RELAXED, __HIP_MEMORY_SCOPE_AGENT);
}
__device__ __forceinline__ void ast(float* p, float v) {
  __hip_atomic_store(p, v, __ATOMIC_RELAXED, __HIP_MEMORY_SCOPE_AGENT);
}
__device__ __forceinline__ unsigned uald(const unsigned* p) {
  return __hip_atomic_load(p, __ATOMIC_RELAXED, __HIP_MEMORY_SCOPE_AGENT);
}
__device__ __forceinline__ void uast(unsigned* p, unsigned v) {
  __hip_atomic_store(p, v, __ATOMIC_RELAXED, __HIP_MEMORY_SCOPE_AGENT);
}

// ---------------------------------------------------------------------------
// Persistent GRU layer scan with PARALLEL-FLAG grid barrier.
// 256 blocks x 256 threads (<= 256 CUs: co-resident).  Block owns 4 j's
// (one wave per j); W_hh read from global (L2-resident, never invalidated —
// no fences anywhere).  h exchanged via agent-scope (sc0 sc1) atomics that
// bypass L1/L2, so no cache maintenance is needed.
// Barrier: block i STORES flags[i] = s (own 64B line — no RMW serialization);
// block 0's 256 threads gather all flags in parallel; block 0 sets rel[s];
// everyone polls rel[s].  flags/rel zeroed by memset before launch -> epochs
// 1..31 never alias stale values across graph replays.
// ---------------------------------------------------------------------------
__global__ __launch_bounds__(256) void gru_persist2_k(
    const float* __restrict__ X,    // [256, 3072] gi
    const float* __restrict__ Whh,  // [3072, 1024]
    const float* __restrict__ bhh,  // [3072]
    float* __restrict__ y,          // [256, 1024] rows; h state per (b,s)
    unsigned* __restrict__ flags,   // 256 slots, 16 uints (64B) apart
    unsigned* __restrict__ rel) {   // 32 slots, 16 uints apart
  __shared__ float hs[8][1024];     // 32 KB
  const int tid = threadIdx.x;
  const int bid = blockIdx.x;
  const int wv = tid >> 6, lane = tid & 63;
  const int j = bid * 4 + wv;
  const float* Wr = Whh + (size_t)j * 1024;
  const float* Wz = Whh + (size_t)(1024 + j) * 1024;
  const float* Wn = Whh + (size_t)(2048 + j) * 1024;
  const float bhr = bhh[j], bhz = bhh[1024 + j], bhn = bhh[2048 + j];
  for (int s = 0; s < 32; ++s) {
    // ---- stage h(s-1) into LDS (agent-scope loads bypass stale L2) ----
    if (s == 0) {
#pragma unroll
      for (int q = 0; q < 8; ++q) {
        int idx = q * 256 + tid;
        *(float4*)&hs[idx >> 8][(idx & 255) * 4] = make_float4(0.f, 0.f, 0.f, 0.f);
      }
    } else {
#pragma unroll
      for (int q = 0; q < 8; ++q) {
        int idx = q * 256 + tid;
        int b = idx >> 8, kf = (idx & 255) * 4;
        const float* hp_ = y + (size_t)(b * 32 + s - 1) * 1024 + kf;
        float4 v;
        v.x = ald(hp_ + 0); v.y = ald(hp_ + 1);
        v.z = ald(hp_ + 2); v.w = ald(hp_ + 3);
        *(float4*)&hs[b][kf] = v;
      }
    }
    __syncthreads();
    // ---- gate dot-products (W from L2-warm global) ----
    float accR[8] = {}, accZ[8] = {}, accN[8] = {};
#pragma unroll
    for (int kk = 0; kk < 4; ++kk) {
      const int k = kk * 256 + lane * 4;
      float4 wr = *(const float4*)&Wr[k];
      float4 wz = *(const float4*)&Wz[k];
      float4 wn = *(const float4*)&Wn[k];
#pragma unroll
      for (int b = 0; b < 8; ++b) {
        float4 h4 = *(const float4*)&hs[b][k];
        accR[b] += h4.x * wr.x + h4.y * wr.y + h4.z * wr.z + h4.w * wr.w;
        accZ[b] += h4.x * wz.x + h4.y * wz.y + h4.z * wz.z + h4.w * wz.w;
        accN[b] += h4.x * wn.x + h4.y * wn.y + h4.z * wn.z + h4.w * wn.w;
      }
    }
#pragma unroll
    for (int d = 1; d < 64; d <<= 1) {
#pragma unroll
      for (int b = 0; b < 8; ++b) {
        accR[b] += __shfl_xor(accR[b], d);
        accZ[b] += __shfl_xor(accZ[b], d);
        accN[b] += __shfl_xor(accN[b], d);
      }
    }
    if (lane < 8) {
      const int b = lane;
      float sr = 0.f, sz = 0.f, sn = 0.f;
#pragma unroll
      for (int bb = 0; bb < 8; ++bb)
        if (b == bb) { sr = accR[bb]; sz = accZ[bb]; sn = accN[bb]; }
      const float* gip = X + (size_t)(b * 32 + s) * 3072;
      float r = 1.0f / (1.0f + __expf(-(gip[j] + sr + bhr)));
      float z = 1.0f / (1.0f + __expf(-(gip[1024 + j] + sz + bhz)));
      float n = tanhf(gip[2048 + j] + r * (sn + bhn));
      float hp = hs[b][j];
      ast(&y[(size_t)(b * 32 + s) * 1024 + j], (1.0f - z) * n + z * hp);
    }
    // ---- grid barrier (parallel flags; no RMW, no fences) ----
    if (s < 31) {
      const unsigned ep = (unsigned)(s + 1);
      __syncthreads();                  // drains vmcnt: y-stores are complete
      if (tid == 0) uast(&flags[bid * 16], ep);
      if (bid == 0) {
        while (uald(&flags[tid * 16]) != ep) __builtin_amdgcn_s_sleep(1);
        __syncthreads();
        if (tid == 0) uast(&rel[s * 16], 1u);
      }
      if (tid == 0) {
        while (uald(&rel[s * 16]) == 0u) __builtin_amdgcn_s_sleep(1);
      }
      __syncthreads();
    }
  }
}

// ---------------------------------------------------------------------------
// X0 GEMM: Cp[z][m][n] = sum_{k in chunk z} A[m,k]*B[n,k]
// A: [256, K] bf16.  B: [N, K] fp32.  M-tile 256 (full M), N-tile 128, BK=32.
// 2-deep register prefetch (ping-pong sets): load issued ~2 MFMA phases
// before its LDS store -> ~800cy to cover HBM latency at 1.5 blocks/CU.
// Requires ksper even (true: 32).
// ---------------------------------------------------------------------------
__global__ __launch_bounds__(256) void gemm_bt16_k(const __bf16* __restrict__ A,
                                                   const float* __restrict__ Bm,
                                                   float* __restrict__ Cp,
                                                   int N, int K, int ksper) {
  __shared__ __bf16 As[256][40];   // 80B row stride: aligned, ~2-way bank alias
  __shared__ __bf16 Bs[128][40];
  const int tid = threadIdx.x;
  const int bn = blockIdx.x * 128;
  const int lane = tid & 63, wv = tid >> 6;
  const int wr = wv >> 1, wc = wv & 1;
  const int lr = lane & 15, kh = lane >> 4;
  const int brow = tid >> 1, bhalf = tid & 1;
  f32x4 acc[8][4] = {};
  const int ks0 = blockIdx.z * ksper;
  const int ks1 = ks0 + ksper;

  uint4 xa0, xa1, xa2, xa3; float4 xb0, xb1, xb2, xb3;   // set X
  uint4 ya0, ya1, ya2, ya3; float4 yb0, yb1, yb2, yb3;   // set Y

  auto loadX = [&](int ks) {
    const int k0 = ks << 5;
    const uint4* ap = (const uint4*)(A + (size_t)tid * K + k0);
    xa0 = ap[0]; xa1 = ap[1]; xa2 = ap[2]; xa3 = ap[3];
    const float* bp = Bm + (size_t)(bn + brow) * K + k0 + bhalf * 16;
    xb0 = ((const float4*)bp)[0]; xb1 = ((const float4*)bp)[1];
    xb2 = ((const float4*)bp)[2]; xb3 = ((const float4*)bp)[3];
  };
  auto loadY = [&](int ks) {
    const int k0 = ks << 5;
    const uint4* ap = (const uint4*)(A + (size_t)tid * K + k0);
    ya0 = ap[0]; ya1 = ap[1]; ya2 = ap[2]; ya3 = ap[3];
    const float* bp = Bm + (size_t)(bn + brow) * K + k0 + bhalf * 16;
    yb0 = ((const float4*)bp)[0]; yb1 = ((const float4*)bp)[1];
    yb2 = ((const float4*)bp)[2]; yb3 = ((const float4*)bp)[3];
  };
  auto storeX = [&]() {
    *(uint4*)&As[tid][0]  = xa0; *(uint4*)&As[tid][8]  = xa1;
    *(uint4*)&As[tid][16] = xa2; *(uint4*)&As[tid][24] = xa3;
    *(bf16x8*)&Bs[brow][bhalf * 16] = cvt8(xb0, xb1);
    *(bf16x8*)&Bs[brow][bhalf * 16 + 8] = cvt8(xb2, xb3);
  };
  auto storeY = [&]() {
    *(uint4*)&As[tid][0]  = ya0; *(uint4*)&As[tid][8]  = ya1;
    *(uint4*)&As[tid][16] = ya2; *(uint4*)&As[tid][24] = ya3;
    *(bf16x8*)&Bs[brow][bhalf * 16] = cvt8(yb0, yb1);
    *(bf16x8*)&Bs[brow][bhalf * 16 + 8] = cvt8(yb2, yb3);
  };
  auto mfmaLDS = [&]() {
    bf16x8 bfv[4];
#pragma unroll
    for (int ni = 0; ni < 4; ++ni)
      bfv[ni] = *(const bf16x8*)&Bs[wc * 64 + ni * 16 + lr][kh * 8];
#pragma unroll
    for (int mi = 0; mi < 8; ++mi) {
      bf16x8 af = *(const bf16x8*)&As[wr * 128 + mi * 16 + lr][kh * 8];
#pragma unroll
      for (int ni = 0; ni < 4; ++ni)
        acc[mi][ni] = __builtin_amdgcn_mfma_f32_16x16x32_bf16(af, bfv[ni],
                                                              acc[mi][ni], 0, 0, 0);
    }
  };

  loadX(ks0);
  loadY(ks0 + 1);
  for (int ks = ks0; ks < ks1; ks += 2) {
    __syncthreads();
    storeX();
    __syncthreads();
    { int nk = ks + 2; if (nk >= ks1) nk = ks1 - 1; loadX(nk); }
    mfmaLDS();
    __syncthreads();
    storeY();
    __syncthreads();
    { int nk = ks + 3; if (nk >= ks1) nk = ks1 - 1; loadY(nk); }
    mfmaLDS();
  }
  float* cp = Cp + (size_t)blockIdx.z * 256 * N;
#pragma unroll
  for (int mi = 0; mi < 8; ++mi) {
#pragma unroll
    for (int ni = 0; ni < 4; ++ni) {
      const int row = wr * 128 + mi * 16 + kh * 4;
      const int col = bn + wc * 64 + ni * 16 + lr;
#pragma unroll
      for (int jj = 0; jj < 4; ++jj)
        cp[(size_t)(row + jj) * N + col] = acc[mi][ni][jj];
    }
  }
}

// ---------------------------------------------------------------------------
// fp32-input MFMA GEMM (he: B [K,N]; X1: B [N,K]) with split-K.
// ---------------------------------------------------------------------------
template <bool BT>
__global__ __launch_bounds__(256) void mfma_gemm_k(const float* __restrict__ A,
                                                   const float* __restrict__ Bm,
                                                   float* __restrict__ Cp,
                                                   int M, int N, int K,
                                                   int lda, int ldb, int ksper) {
  __shared__ __bf16 As[128][40];
  __shared__ __bf16 Bs[128][40];
  const int tid = threadIdx.x;
  const int bm = blockIdx.y * 128, bn = blockIdx.x * 128;
  const int lane = tid & 63, wv = tid >> 6;
  const int wr = wv >> 1, wc = wv & 1;
  const int lr = lane & 15, kh = lane >> 4;
  f32x4 acc[4][4] = {};
  const int kstot = K >> 5;
  int ks0 = blockIdx.z * ksper;
  int ks1 = ks0 + ksper; if (ks1 > kstot) ks1 = kstot;
  for (int ks = ks0; ks < ks1; ++ks) {
    const int k0 = ks << 5;
    __syncthreads();
    {
      const int row = tid >> 1, half = tid & 1;
      const float* ap = A + (size_t)(bm + row) * lda + k0 + half * 16;
      float4 f0 = ((const float4*)ap)[0], f1 = ((const float4*)ap)[1];
      float4 f2 = ((const float4*)ap)[2], f3 = ((const float4*)ap)[3];
      *(bf16x8*)&As[row][half * 16] = cvt8(f0, f1);
      *(bf16x8*)&As[row][half * 16 + 8] = cvt8(f2, f3);
    }
    if (BT) {
      const int row = tid >> 1, half = tid & 1;
      const float* bp = Bm + (size_t)(bn + row) * ldb + k0 + half * 16;
      float4 f0 = ((const float4*)bp)[0], f1 = ((const float4*)bp)[1];
      float4 f2 = ((const float4*)bp)[2], f3 = ((const float4*)bp)[3];
      *(bf16x8*)&Bs[row][half * 16] = cvt8(f0, f1);
      *(bf16x8*)&Bs[row][half * 16 + 8] = cvt8(f2, f3);
    } else {
      const int kk = tid >> 3, ng = tid & 7;
      const float* bp = Bm + (size_t)(k0 + kk) * ldb + bn + ng * 16;
      float4 f[4];
#pragma unroll
      for (int q = 0; q < 4; ++q) f[q] = ((const float4*)bp)[q];
#pragma unroll
      for (int q = 0; q < 4; ++q) {
        Bs[ng * 16 + q * 4 + 0][kk] = (__bf16)f[q].x;
        Bs[ng * 16 + q * 4 + 1][kk] = (__bf16)f[q].y;
        Bs[ng * 16 + q * 4 + 2][kk] = (__bf16)f[q].z;
        Bs[ng * 16 + q * 4 + 3][kk] = (__bf16)f[q].w;
      }
    }
    __syncthreads();
    bf16x8 af[4], bfv[4];
#pragma unroll
    for (int mi = 0; mi < 4; ++mi)
      af[mi] = *(const bf16x8*)&As[wr * 64 + mi * 16 + lr][kh * 8];
#pragma unroll
    for (int ni = 0; ni < 4; ++ni)
      bfv[ni] = *(const bf16x8*)&Bs[wc * 64 + ni * 16 + lr][kh * 8];
#pragma unroll
    for (int mi = 0; mi < 4; ++mi)
#pragma unroll
      for (int ni = 0; ni < 4; ++ni)
        acc[mi][ni] = __builtin_amdgcn_mfma_f32_16x16x32_bf16(af[mi], bfv[ni],
                                                              acc[mi][ni], 0, 0, 0);
  }
  float* cp = Cp + (size_t)blockIdx.z * M * N;
#pragma unroll
  for (int mi = 0; mi < 4; ++mi) {
#pragma unroll
    for (int ni = 0; ni < 4; ++ni) {
      const int row = bm + wr * 64 + mi * 16 + kh * 4;
      const int col = bn + wc * 64 + ni * 16 + lr;
#pragma unroll
      for (int j = 0; j < 4; ++j)
        cp[(size_t)(row + j) * N + col] = acc[mi][ni][j];
    }
  }
}

// C[i] = bias[i%N] + sum_sk Cp[sk][i]
__global__ __launch_bounds__(256) void reduce_k(const float* __restrict__ Cp,
                                                const float* __restrict__ bias,
                                                float* __restrict__ C,
                                                int MN, int N, int nsk) {
  int i = (blockIdx.x * 256 + threadIdx.x) * 4;
  if (i >= MN) return;
  float4 s = make_float4(0.f, 0.f, 0.f, 0.f);
  if (bias) s = *(const float4*)&bias[i % N];
  for (int sk = 0; sk < nsk; ++sk) {
    float4 p = *(const float4*)&Cp[(size_t)sk * MN + i];
    s.x += p.x; s.y += p.y; s.z += p.z; s.w += p.w;
  }
  *(float4*)&C[i] = s;
}

// ---------------------------------------------------------------------------
// h[g,n,c] = he[g,c] + sum_f x_node[g,n,f] * Wg[f,c]   -> stored bf16
// ---------------------------------------------------------------------------
__global__ __launch_bounds__(256) void node_h_k(const float* __restrict__ xn,
                                                const float* __restrict__ Wg,
                                                const float* __restrict__ he,
                                                bf16* __restrict__ hbuf) {
  __shared__ float xns[64][32];
  __shared__ float wgs[32][256];
  const int cq = blockIdx.x, g = blockIdx.y;
  const int tid = threadIdx.x;
  for (int idx = tid; idx < 2048; idx += 256) xns[idx >> 5][idx & 31] = xn[g * 2048 + idx];
  for (int r = 0; r < 32; ++r) wgs[r][tid] = Wg[r * 1024 + cq * 256 + tid];
  __syncthreads();
  const float hev = he[g * 1024 + cq * 256 + tid];
  for (int n0 = 0; n0 < 64; n0 += 8) {
    float acc[8];
#pragma unroll
    for (int nn = 0; nn < 8; ++nn) acc[nn] = hev;
    for (int f = 0; f < 32; ++f) {
      float w = wgs[f][tid];
#pragma unroll
      for (int nn = 0; nn < 8; ++nn) acc[nn] += xns[n0 + nn][f] * w;
    }
#pragma unroll
    for (int nn = 0; nn < 8; ++nn)
      hbuf[(size_t)(g * 64 + n0 + nn) * 1024 + cq * 256 + tid] = __float2bfloat16(acc[nn]);
  }
}

// ---------------------------------------------------------------------------
// a_s[row,hd] = sum_e h[row, hd*256+e] * att_src[hd,e]; same for a_d.
// ---------------------------------------------------------------------------
__global__ __launch_bounds__(256) void as_ad_k(const bf16* __restrict__ hbuf,
                                               const float* __restrict__ att_s,
                                               const float* __restrict__ att_d,
                                               float* __restrict__ as_o,
                                               float* __restrict__ ad_o) {
  const int tid = threadIdx.x;
  const int lane = tid & 63, wv = tid >> 6;
  const int row = blockIdx.x * 4 + wv;
  const int hd = lane >> 4;
  const int e0 = (lane & 15) * 16;
  float as_r[16], ad_r[16];
#pragma unroll
  for (int q = 0; q < 4; ++q) {
    float4 v = *(const float4*)(att_s + hd * 256 + e0 + q * 4);
    as_r[q * 4 + 0] = v.x; as_r[q * 4 + 1] = v.y; as_r[q * 4 + 2] = v.z; as_r[q * 4 + 3] = v.w;
    float4 w = *(const float4*)(att_d + hd * 256 + e0 + q * 4);
    ad_r[q * 4 + 0] = w.x; ad_r[q * 4 + 1] = w.y; ad_r[q * 4 + 2] = w.z; ad_r[q * 4 + 3] = w.w;
  }
  const uint4* hp = (const uint4*)(hbuf + (size_t)row * 1024 + lane * 16);
  uint4 p0 = hp[0], p1 = hp[1];
  float hv[16];
  unp2(p0.x, hv[0], hv[1]);  unp2(p0.y, hv[2], hv[3]);
  unp2(p0.z, hv[4], hv[5]);  unp2(p0.w, hv[6], hv[7]);
  unp2(p1.x, hv[8], hv[9]);  unp2(p1.y, hv[10], hv[11]);
  unp2(p1.z, hv[12], hv[13]); unp2(p1.w, hv[14], hv[15]);
  float ps = 0.f, pd = 0.f;
#pragma unroll
  for (int i = 0; i < 16; ++i) { ps += as_r[i] * hv[i]; pd += ad_r[i] * hv[i]; }
#pragma unroll
  for (int m = 1; m < 16; m <<= 1) { ps += __shfl_xor(ps, m); pd += __shfl_xor(pd, m); }
  if ((lane & 15) == 0) { as_o[row * 4 + hd] = ps; ad_o[row * 4 + hd] = pd; }
}

// ---------------------------------------------------------------------------
// Per graph g: softmax over sources + head-mean aggregation + bias + relu.
// ---------------------------------------------------------------------------
__global__ __launch_bounds__(256) void attn_agg_k(const bf16* __restrict__ hbuf,
                                                  const float* __restrict__ as_i,
                                                  const float* __restrict__ ad_i,
                                                  const float* __restrict__ bgat,
                                                  __bf16* __restrict__ seq) {
  __shared__ float ass[256], ads[256], bgs[256];
  __shared__ float alpha[4][64][64];   // [hd][j][i]
  __shared__ float hq[64][260];        // one head-quarter of h, fp32
  const int g = blockIdx.x, tid = threadIdx.x;
  ass[tid] = as_i[g * 256 + tid];
  ads[tid] = ad_i[g * 256 + tid];
  bgs[tid] = bgat[tid];
  __syncthreads();
  {
    const int hd = tid >> 6, i = tid & 63;
    const float ad = ads[i * 4 + hd];
    float m = -1e30f;
    for (int j = 0; j < 64; ++j) {
      float s = ad + ass[j * 4 + hd];
      s = s > 0.0f ? s : 0.2f * s;
      m = fmaxf(m, s);
    }
    float sum = 0.0f;
    for (int j = 0; j < 64; ++j) {
      float s = ad + ass[j * 4 + hd];
      s = s > 0.0f ? s : 0.2f * s;
      sum += __expf(s - m);
    }
    const float inv = 1.0f / sum;
    for (int j = 0; j < 64; ++j) {
      float s = ad + ass[j * 4 + hd];
      s = s > 0.0f ? s : 0.2f * s;
      alpha[hd][j][i] = __expf(s - m) * inv;
    }
  }
  const int i = tid & 63, eq = tid >> 6;
  float acc[64] = {};
  for (int hd = 0; hd < 4; ++hd) {
    __syncthreads();
    for (int idx = tid; idx < 2048; idx += 256) {
      int j = idx >> 5, ch = idx & 31;
      uint4 p = *(const uint4*)(hbuf + (size_t)(g * 64 + j) * 1024 + hd * 256 + ch * 8);
      float f0, f1, f2, f3, f4, f5, f6, f7;
      unp2(p.x, f0, f1); unp2(p.y, f2, f3); unp2(p.z, f4, f5); unp2(p.w, f6, f7);
      *(float4*)&hq[j][ch * 8] = make_float4(f0, f1, f2, f3);
      *(float4*)&hq[j][ch * 8 + 4] = make_float4(f4, f5, f6, f7);
    }
    __syncthreads();
    for (int j = 0; j < 64; ++j) {
      const float a = alpha[hd][j][i];
      const float* hr = &hq[j][eq * 64];
#pragma unroll
      for (int q = 0; q < 16; ++q) {
        float4 hv = *(const float4*)(hr + q * 4);
        acc[q * 4 + 0] += a * hv.x; acc[q * 4 + 1] += a * hv.y;
        acc[q * 4 + 2] += a * hv.z; acc[q * 4 + 3] += a * hv.w;
      }
    }
  }
  __bf16* op = seq + (size_t)g * 16384 + i * 256 + eq * 64;
#pragma unroll
  for (int q = 0; q < 8; ++q) {
    float4 lo, hi;
    lo.x = fmaxf(bgs[eq * 64 + q * 8 + 0] + 0.25f * acc[q * 8 + 0], 0.0f);
    lo.y = fmaxf(bgs[eq * 64 + q * 8 + 1] + 0.25f * acc[q * 8 + 1], 0.0f);
    lo.z = fmaxf(bgs[eq * 64 + q * 8 + 2] + 0.25f * acc[q * 8 + 2], 0.0f);
    lo.w = fmaxf(bgs[eq * 64 + q * 8 + 3] + 0.25f * acc[q * 8 + 3], 0.0f);
    hi.x = fmaxf(bgs[eq * 64 + q * 8 + 4] + 0.25f * acc[q * 8 + 4], 0.0f);
    hi.y = fmaxf(bgs[eq * 64 + q * 8 + 5] + 0.25f * acc[q * 8 + 5], 0.0f);
    hi.z = fmaxf(bgs[eq * 64 + q * 8 + 6] + 0.25f * acc[q * 8 + 6], 0.0f);
    hi.w = fmaxf(bgs[eq * 64 + q * 8 + 7] + 0.25f * acc[q * 8 + 7], 0.0f);
    *(bf16x8*)(op + q * 8) = cvt8(lo, hi);
  }
}

// ---------------------------------------------------------------------------
// out[b,o] = b_fc[o] + sum_k y1[b,31,k] * Wfc[k,o]
// ---------------------------------------------------------------------------
__global__ __launch_bounds__(256) void fc_k(const float* __restrict__ y1,
                                            const float* __restrict__ Wfc,
                                            const float* __restrict__ bfc,
                                            float* __restrict__ out) {
  __shared__ float As[8][1024];
  const int tid = threadIdx.x;
  for (int idx = tid; idx < 8192; idx += 256) {
    int b = idx >> 10, k = idx & 1023;
    As[b][k] = y1[(size_t)(b * 32 + 31) * 1024 + k];
  }
  __syncthreads();
  const int ol = tid >> 2, kq = tid & 3;
  const int o = blockIdx.x * 64 + ol;
  float acc[8] = {};
  if (o < 2016) {
    for (int i2 = 0; i2 < 256; ++i2) {
      int k = i2 * 4 + kq;
      float w = Wfc[(size_t)k * 2016 + o];
#pragma unroll
      for (int b = 0; b < 8; ++b) acc[b] += As[b][k] * w;
    }
  }
#pragma unroll
  for (int b = 0; b < 8; ++b) {
    acc[b] += __shfl_xor(acc[b], 1);
    acc[b] += __shfl_xor(acc[b], 2);
  }
  if (kq == 0 && o < 2016) {
#pragma unroll
    for (int b = 0; b < 8; ++b) out[b * 2016 + o] = acc[b] + bfc[o];
  }
}

// ---------------------------------------------------------------------------
extern "C" void kernel_launch(void* const* d_in, const int* in_sizes, int n_in,
                              void* d_out, int out_size, void* d_ws, size_t ws_size,
                              hipStream_t stream) {
  (void)in_sizes; (void)n_in; (void)out_size; (void)ws_size;
  const float* x_node = (const float*)d_in[0];
  const float* x_edge = (const float*)d_in[1];
  // d_in[2] = edge_index: complete graph + self loops -> dense; unused.
  const float* W_gat = (const float*)d_in[3];
  const float* att_s = (const float*)d_in[4];
  const float* att_d = (const float*)d_in[5];
  const float* b_gat = (const float*)d_in[6];
  const float* W_ih0 = (const float*)d_in[7];
  const float* W_hh0 = (const float*)d_in[8];
  const float* b_ih0 = (const float*)d_in[9];
  const float* b_hh0 = (const float*)d_in[10];
  const float* W_ih1 = (const float*)d_in[11];
  const float* W_hh1 = (const float*)d_in[12];
  const float* b_ih1 = (const float*)d_in[13];
  const float* b_hh1 = (const float*)d_in[14];
  const float* W_fc  = (const float*)d_in[15];
  const float* b_fc  = (const float*)d_in[16];

  char* ws = (char*)d_ws;
  size_t off = 0;
  float*  he  = (float*)(ws + off);  off += 256u * 1024 * 4;           // 1 MB
  float*  a_s = (float*)(ws + off);  off += 256u * 64 * 4 * 4;         // 256 KB
  float*  a_d = (float*)(ws + off);  off += 256u * 64 * 4 * 4;         // 256 KB
  bf16*   hb  = (bf16*)(ws + off);   off += 256u * 64 * 1024 * 2;      // 32 MB
  __bf16* seq = (__bf16*)(ws + off); off += 256u * 16384 * 2;          // 8 MB
  float*  X0  = (float*)(ws + off);  off += 256u * 3072 * 4;           // 3 MB
  float*  y0  = (float*)(ws + off);  off += 256u * 1024 * 4;           // 1 MB
  float*  X1  = (float*)(ws + off);  off += 256u * 3072 * 4;           // 3 MB
  float*  y1  = (float*)(ws + off);  off += 256u * 1024 * 4;           // 1 MB
  off = (off + 255) & ~(size_t)255;
  unsigned* flags = (unsigned*)(ws + off); off += 256u * 64;           // 16 KB
  unsigned* rel   = (unsigned*)(ws + off); off += 32u * 64;            // 2 KB
  float*  Cp  = (float*)(ws + off);  off += (size_t)16 * 256 * 3072 * 4; // 48 MB

  // 1) he = x_edge @ W_gat[32:, :]   (M=256, N=1024, K=2016, B is [K,N]) SK=8
  mfma_gemm_k<false><<<dim3(8, 2, 8), 256, 0, stream>>>(
      x_edge, W_gat + 32 * 1024, Cp, 256, 1024, 2016, 2016, 1024, 8);
  reduce_k<<<256, 256, 0, stream>>>(Cp, nullptr, he, 256 * 1024, 1024, 8);
  // 2) h = node-proj + he (bf16)
  node_h_k<<<dim3(4, 256), 256, 0, stream>>>(x_node, W_gat, he, hb);
  // 3) attention logits
  as_ad_k<<<4096, 256, 0, stream>>>(hb, att_s, att_d, a_s, a_d);
  // 4) softmax + aggregation + relu -> seq [256, 16384] bf16
  attn_agg_k<<<256, 256, 0, stream>>>(hb, a_s, a_d, b_gat, seq);
  // 5) X0 = seq @ W_ih0^T + b_ih0   (M=256 full-tile, N=3072, K=16384) SK=16
  gemm_bt16_k<<<dim3(24, 1, 16), 256, 0, stream>>>(seq, W_ih0, Cp,
                                                   3072, 16384, 32);
  reduce_k<<<768, 256, 0, stream>>>(Cp, b_ih0, X0, 256 * 3072, 3072, 16);
  // 6) GRU layer 0: persistent scan, parallel-flag barrier
  hipMemsetAsync(flags, 0, 256u * 64 + 32u * 64, stream);
  gru_persist2_k<<<256, 256, 0, stream>>>(X0, W_hh0, b_hh0, y0, flags, rel);
  // 7) X1 = y0 @ W_ih1^T + b_ih1    (M=256, N=3072, K=1024) SK=4
  mfma_gemm_k<true><<<dim3(24, 2, 4), 256, 0, stream>>>(
      y0, W_ih1, Cp, 256, 3072, 1024, 1024, 1024, 8);
  reduce_k<<<768, 256, 0, stream>>>(Cp, b_ih1, X1, 256 * 3072, 3072, 4);
  // 8) GRU layer 1: persistent scan
  hipMemsetAsync(flags, 0, 256u * 64 + 32u * 64, stream);
  gru_persist2_k<<<256, 256, 0, stream>>>(X1, W_hh1, b_hh1, y1, flags, rel);
  // 9) out = y1[:, 31] @ W_fc + b_fc
  fc_k<<<32, 256, 0, stream>>>(y1, W_fc, b_fc, (float*)d_out);
}

// Round 9
// 765.410 us; speedup vs baseline: 1.1134x; 1.1134x over previous
//
#include <hip/hip_runtime.h>
#include <hip/hip_bf16.h>

using bf16 = __hip_bfloat16;
typedef __bf16 bf16x8 __attribute__((ext_vector_type(8)));
typedef float f32x4 __attribute__((ext_vector_type(4)));

// Sizes (fixed): B=8 S=32 N=64 F_NODE=32 TRI=2016 DIN=2048 H=4 DOUT=256 R=1024
// OUT=2016, G=B*S=256 graphs

__device__ __forceinline__ void unp2(unsigned int u, float& a, float& b) {
  a = __uint_as_float(u << 16);
  b = __uint_as_float(u & 0xffff0000u);
}

__device__ __forceinline__ bf16x8 cvt8(float4 a, float4 b) {
  bf16x8 r;
  r[0] = (__bf16)a.x; r[1] = (__bf16)a.y; r[2] = (__bf16)a.z; r[3] = (__bf16)a.w;
  r[4] = (__bf16)b.x; r[5] = (__bf16)b.y; r[6] = (__bf16)b.z; r[7] = (__bf16)b.w;
  return r;
}

// ---------------------------------------------------------------------------
// Fused two-layer GRU step, software-pipelined across launches.
// Launch t (t = 0..32):
//   blocks [0,256):   layer 0, step t     (skip if t==32)  — 4 j's, wave per j
//   blocks [256,512): layer 1, step t-1   (skip if t==0)   — 4 j's, wave per j;
//     folds the input projection gi = y0[t-1] @ W_ih1^T + b_ih1 (fp32 GEMV)
//     so no separate X1 GEMM is needed.
// All inter-launch dataflow via global memory (kernel-boundary coherence).
// W rows are read from global and stay L2-resident across the 33 launches.
// ---------------------------------------------------------------------------
__global__ __launch_bounds__(256) void gru_fused_k(
    const float* __restrict__ X0,    // [256, 3072] layer-0 gi
    const float* __restrict__ Whh0,  // [3072, 1024]
    const float* __restrict__ bhh0,  // [3072]
    float* __restrict__ y0,          // [256, 1024]
    const float* __restrict__ Wih1,  // [3072, 1024]
    const float* __restrict__ bih1,  // [3072]
    const float* __restrict__ Whh1,  // [3072, 1024]
    const float* __restrict__ bhh1,  // [3072]
    float* __restrict__ y1,          // [256, 1024]
    int t) {
  __shared__ float sA[8][1024];      // layer0: h(t-1) ; layer1: y0[t-1]
  __shared__ float sB[8][1024];      // layer1: y1[t-2]
  const int tid = threadIdx.x;
  const int wv = tid >> 6, lane = tid & 63;

  if (blockIdx.x < 256) {
    // ------------------------- layer 0, step t -------------------------
    if (t >= 32) return;
    const int s = t;
    if (s == 0) {
#pragma unroll
      for (int q = 0; q < 8; ++q) {
        int idx = q * 256 + tid;
        *(float4*)&sA[idx >> 8][(idx & 255) * 4] = make_float4(0.f, 0.f, 0.f, 0.f);
      }
    } else {
#pragma unroll
      for (int q = 0; q < 8; ++q) {
        int idx = q * 256 + tid;
        int b = idx >> 8, kf = (idx & 255) * 4;
        *(float4*)&sA[b][kf] =
            *(const float4*)&y0[(size_t)(b * 32 + s - 1) * 1024 + kf];
      }
    }
    __syncthreads();
    const int j = blockIdx.x * 4 + wv;
    const float* Wr = Whh0 + (size_t)j * 1024;
    const float* Wz = Whh0 + (size_t)(1024 + j) * 1024;
    const float* Wn = Whh0 + (size_t)(2048 + j) * 1024;
    float accR[8] = {}, accZ[8] = {}, accN[8] = {};
#pragma unroll
    for (int kk = 0; kk < 4; ++kk) {
      const int k = kk * 256 + lane * 4;
      float4 wr = *(const float4*)&Wr[k];
      float4 wz = *(const float4*)&Wz[k];
      float4 wn = *(const float4*)&Wn[k];
#pragma unroll
      for (int b = 0; b < 8; ++b) {
        float4 h4 = *(const float4*)&sA[b][k];
        accR[b] += h4.x * wr.x + h4.y * wr.y + h4.z * wr.z + h4.w * wr.w;
        accZ[b] += h4.x * wz.x + h4.y * wz.y + h4.z * wz.z + h4.w * wz.w;
        accN[b] += h4.x * wn.x + h4.y * wn.y + h4.z * wn.z + h4.w * wn.w;
      }
    }
#pragma unroll
    for (int d = 1; d < 64; d <<= 1) {
#pragma unroll
      for (int b = 0; b < 8; ++b) {
        accR[b] += __shfl_xor(accR[b], d);
        accZ[b] += __shfl_xor(accZ[b], d);
        accN[b] += __shfl_xor(accN[b], d);
      }
    }
    if (lane < 8) {
      const int b = lane;
      float sr = 0.f, sz = 0.f, sn = 0.f;
#pragma unroll
      for (int bb = 0; bb < 8; ++bb)
        if (b == bb) { sr = accR[bb]; sz = accZ[bb]; sn = accN[bb]; }
      const float* gip = X0 + (size_t)(b * 32 + s) * 3072;
      float r = 1.0f / (1.0f + __expf(-(gip[j] + sr + bhh0[j])));
      float z = 1.0f / (1.0f + __expf(-(gip[1024 + j] + sz + bhh0[1024 + j])));
      float n = tanhf(gip[2048 + j] + r * (sn + bhh0[2048 + j]));
      float hp = sA[b][j];
      y0[(size_t)(b * 32 + s) * 1024 + j] = (1.0f - z) * n + z * hp;
    }
  } else {
    // ------------------------- layer 1, step t-1 -------------------------
    if (t < 1) return;
    const int s = t - 1;
    {
#pragma unroll
      for (int q = 0; q < 8; ++q) {
        int idx = q * 256 + tid;
        int b = idx >> 8, kf = (idx & 255) * 4;
        *(float4*)&sA[b][kf] =
            *(const float4*)&y0[(size_t)(b * 32 + s) * 1024 + kf];
        float4 v = make_float4(0.f, 0.f, 0.f, 0.f);
        if (s > 0)
          v = *(const float4*)&y1[(size_t)(b * 32 + s - 1) * 1024 + kf];
        *(float4*)&sB[b][kf] = v;
      }
    }
    __syncthreads();
    const int j = (blockIdx.x - 256) * 4 + wv;
    const float* WiR = Wih1 + (size_t)j * 1024;
    const float* WiZ = Wih1 + (size_t)(1024 + j) * 1024;
    const float* WiN = Wih1 + (size_t)(2048 + j) * 1024;
    const float* WhR = Whh1 + (size_t)j * 1024;
    const float* WhZ = Whh1 + (size_t)(1024 + j) * 1024;
    const float* WhN = Whh1 + (size_t)(2048 + j) * 1024;
    // i_r+h_r and i_z+h_z are only used summed -> reduce as combined arrays.
    float accRZ[8] = {}, accZZ[8] = {}, accIN[8] = {}, accHN[8] = {};
#pragma unroll
    for (int kk = 0; kk < 4; ++kk) {
      const int k = kk * 256 + lane * 4;
      float4 wir = *(const float4*)&WiR[k];
      float4 wiz = *(const float4*)&WiZ[k];
      float4 win = *(const float4*)&WiN[k];
      float4 whr = *(const float4*)&WhR[k];
      float4 whz = *(const float4*)&WhZ[k];
      float4 whn = *(const float4*)&WhN[k];
#pragma unroll
      for (int b = 0; b < 8; ++b) {
        float4 x4 = *(const float4*)&sA[b][k];   // y0[t-1] (= x_t of layer 1)
        float4 h4 = *(const float4*)&sB[b][k];   // y1[t-2]
        accRZ[b] += x4.x * wir.x + x4.y * wir.y + x4.z * wir.z + x4.w * wir.w
                  + h4.x * whr.x + h4.y * whr.y + h4.z * whr.z + h4.w * whr.w;
        accZZ[b] += x4.x * wiz.x + x4.y * wiz.y + x4.z * wiz.z + x4.w * wiz.w
                  + h4.x * whz.x + h4.y * whz.y + h4.z * whz.z + h4.w * whz.w;
        accIN[b] += x4.x * win.x + x4.y * win.y + x4.z * win.z + x4.w * win.w;
        accHN[b] += h4.x * whn.x + h4.y * whn.y + h4.z * whn.z + h4.w * whn.w;
      }
    }
#pragma unroll
    for (int d = 1; d < 64; d <<= 1) {
#pragma unroll
      for (int b = 0; b < 8; ++b) {
        accRZ[b] += __shfl_xor(accRZ[b], d);
        accZZ[b] += __shfl_xor(accZZ[b], d);
        accIN[b] += __shfl_xor(accIN[b], d);
        accHN[b] += __shfl_xor(accHN[b], d);
      }
    }
    if (lane < 8) {
      const int b = lane;
      float srz = 0.f, szz = 0.f, sin_ = 0.f, shn = 0.f;
#pragma unroll
      for (int bb = 0; bb < 8; ++bb)
        if (b == bb) { srz = accRZ[bb]; szz = accZZ[bb]; sin_ = accIN[bb]; shn = accHN[bb]; }
      float r = 1.0f / (1.0f + __expf(-(srz + bih1[j] + bhh1[j])));
      float z = 1.0f / (1.0f + __expf(-(szz + bih1[1024 + j] + bhh1[1024 + j])));
      float n = tanhf(sin_ + bih1[2048 + j] + r * (shn + bhh1[2048 + j]));
      float hp = sB[b][j];
      y1[(size_t)(b * 32 + s) * 1024 + j] = (1.0f - z) * n + z * hp;
    }
  }
}

// ---------------------------------------------------------------------------
// X0 GEMM: Cp[z][m][n] = sum_{k in chunk z} A[m,k]*B[n,k]
// A: [256, K] bf16 (full 32 bf16/row staged).  B: [N, K] fp32.
// M-tile = 256 (full M), N-tile 128, BK=32, 1-deep register prefetch (proven).
// ---------------------------------------------------------------------------
__global__ __launch_bounds__(256) void gemm_bt16_k(const __bf16* __restrict__ A,
                                                   const float* __restrict__ Bm,
                                                   float* __restrict__ Cp,
                                                   int N, int K, int ksper) {
  __shared__ __bf16 As[256][40];   // 80B row stride: aligned, ~2-way bank alias
  __shared__ __bf16 Bs[128][40];
  const int tid = threadIdx.x;
  const int bn = blockIdx.x * 128;
  const int lane = tid & 63, wv = tid >> 6;
  const int wr = wv >> 1, wc = wv & 1;
  const int lr = lane & 15, kh = lane >> 4;
  const int brow = tid >> 1, bhalf = tid & 1;
  f32x4 acc[8][4] = {};
  const int kstot = K >> 5;
  int ks0 = blockIdx.z * ksper;
  int ks1 = ks0 + ksper; if (ks1 > kstot) ks1 = kstot;
  uint4 ra0, ra1, ra2, ra3; float4 rb0, rb1, rb2, rb3;
  {
    const int k0 = ks0 << 5;
    const uint4* ap = (const uint4*)(A + (size_t)tid * K + k0);
    ra0 = ap[0]; ra1 = ap[1]; ra2 = ap[2]; ra3 = ap[3];
    const float* bp = Bm + (size_t)(bn + brow) * K + k0 + bhalf * 16;
    rb0 = ((const float4*)bp)[0]; rb1 = ((const float4*)bp)[1];
    rb2 = ((const float4*)bp)[2]; rb3 = ((const float4*)bp)[3];
  }
  for (int ks = ks0; ks < ks1; ++ks) {
    __syncthreads();
    *(uint4*)&As[tid][0]  = ra0;
    *(uint4*)&As[tid][8]  = ra1;
    *(uint4*)&As[tid][16] = ra2;
    *(uint4*)&As[tid][24] = ra3;
    *(bf16x8*)&Bs[brow][bhalf * 16] = cvt8(rb0, rb1);
    *(bf16x8*)&Bs[brow][bhalf * 16 + 8] = cvt8(rb2, rb3);
    __syncthreads();
    if (ks + 1 < ks1) {  // prefetch next K-tile into regs; overlaps with MFMA
      const int k0 = (ks + 1) << 5;
      const uint4* ap = (const uint4*)(A + (size_t)tid * K + k0);
      ra0 = ap[0]; ra1 = ap[1]; ra2 = ap[2]; ra3 = ap[3];
      const float* bp = Bm + (size_t)(bn + brow) * K + k0 + bhalf * 16;
      rb0 = ((const float4*)bp)[0]; rb1 = ((const float4*)bp)[1];
      rb2 = ((const float4*)bp)[2]; rb3 = ((const float4*)bp)[3];
    }
    bf16x8 bfv[4];
#pragma unroll
    for (int ni = 0; ni < 4; ++ni)
      bfv[ni] = *(const bf16x8*)&Bs[wc * 64 + ni * 16 + lr][kh * 8];
#pragma unroll
    for (int mi = 0; mi < 8; ++mi) {
      bf16x8 af = *(const bf16x8*)&As[wr * 128 + mi * 16 + lr][kh * 8];
#pragma unroll
      for (int ni = 0; ni < 4; ++ni)
        acc[mi][ni] = __builtin_amdgcn_mfma_f32_16x16x32_bf16(af, bfv[ni],
                                                              acc[mi][ni], 0, 0, 0);
    }
  }
  float* cp = Cp + (size_t)blockIdx.z * 256 * N;
#pragma unroll
  for (int mi = 0; mi < 8; ++mi) {
#pragma unroll
    for (int ni = 0; ni < 4; ++ni) {
      const int row = wr * 128 + mi * 16 + kh * 4;
      const int col = bn + wc * 64 + ni * 16 + lr;
#pragma unroll
      for (int j = 0; j < 4; ++j)
        cp[(size_t)(row + j) * N + col] = acc[mi][ni][j];
    }
  }
}

// ---------------------------------------------------------------------------
// fp32-input MFMA GEMM (he: B [K,N]) with split-K.
// ---------------------------------------------------------------------------
template <bool BT>
__global__ __launch_bounds__(256) void mfma_gemm_k(const float* __restrict__ A,
                                                   const float* __restrict__ Bm,
                                                   float* __restrict__ Cp,
                                                   int M, int N, int K,
                                                   int lda, int ldb, int ksper) {
  __shared__ __bf16 As[128][40];
  __shared__ __bf16 Bs[128][40];
  const int tid = threadIdx.x;
  const int bm = blockIdx.y * 128, bn = blockIdx.x * 128;
  const int lane = tid & 63, wv = tid >> 6;
  const int wr = wv >> 1, wc = wv & 1;
  const int lr = lane & 15, kh = lane >> 4;
  f32x4 acc[4][4] = {};
  const int kstot = K >> 5;
  int ks0 = blockIdx.z * ksper;
  int ks1 = ks0 + ksper; if (ks1 > kstot) ks1 = kstot;
  for (int ks = ks0; ks < ks1; ++ks) {
    const int k0 = ks << 5;
    __syncthreads();
    {
      const int row = tid >> 1, half = tid & 1;
      const float* ap = A + (size_t)(bm + row) * lda + k0 + half * 16;
      float4 f0 = ((const float4*)ap)[0], f1 = ((const float4*)ap)[1];
      float4 f2 = ((const float4*)ap)[2], f3 = ((const float4*)ap)[3];
      *(bf16x8*)&As[row][half * 16] = cvt8(f0, f1);
      *(bf16x8*)&As[row][half * 16 + 8] = cvt8(f2, f3);
    }
    if (BT) {
      const int row = tid >> 1, half = tid & 1;
      const float* bp = Bm + (size_t)(bn + row) * ldb + k0 + half * 16;
      float4 f0 = ((const float4*)bp)[0], f1 = ((const float4*)bp)[1];
      float4 f2 = ((const float4*)bp)[2], f3 = ((const float4*)bp)[3];
      *(bf16x8*)&Bs[row][half * 16] = cvt8(f0, f1);
      *(bf16x8*)&Bs[row][half * 16 + 8] = cvt8(f2, f3);
    } else {
      const int kk = tid >> 3, ng = tid & 7;
      const float* bp = Bm + (size_t)(k0 + kk) * ldb + bn + ng * 16;
      float4 f[4];
#pragma unroll
      for (int q = 0; q < 4; ++q) f[q] = ((const float4*)bp)[q];
#pragma unroll
      for (int q = 0; q < 4; ++q) {
        Bs[ng * 16 + q * 4 + 0][kk] = (__bf16)f[q].x;
        Bs[ng * 16 + q * 4 + 1][kk] = (__bf16)f[q].y;
        Bs[ng * 16 + q * 4 + 2][kk] = (__bf16)f[q].z;
        Bs[ng * 16 + q * 4 + 3][kk] = (__bf16)f[q].w;
      }
    }
    __syncthreads();
    bf16x8 af[4], bfv[4];
#pragma unroll
    for (int mi = 0; mi < 4; ++mi)
      af[mi] = *(const bf16x8*)&As[wr * 64 + mi * 16 + lr][kh * 8];
#pragma unroll
    for (int ni = 0; ni < 4; ++ni)
      bfv[ni] = *(const bf16x8*)&Bs[wc * 64 + ni * 16 + lr][kh * 8];
#pragma unroll
    for (int mi = 0; mi < 4; ++mi)
#pragma unroll
      for (int ni = 0; ni < 4; ++ni)
        acc[mi][ni] = __builtin_amdgcn_mfma_f32_16x16x32_bf16(af[mi], bfv[ni],
                                                              acc[mi][ni], 0, 0, 0);
  }
  float* cp = Cp + (size_t)blockIdx.z * M * N;
#pragma unroll
  for (int mi = 0; mi < 4; ++mi) {
#pragma unroll
    for (int ni = 0; ni < 4; ++ni) {
      const int row = bm + wr * 64 + mi * 16 + kh * 4;
      const int col = bn + wc * 64 + ni * 16 + lr;
#pragma unroll
      for (int j = 0; j < 4; ++j)
        cp[(size_t)(row + j) * N + col] = acc[mi][ni][j];
    }
  }
}

// C[i] = bias[i%N] + sum_sk Cp[sk][i]
__global__ __launch_bounds__(256) void reduce_k(const float* __restrict__ Cp,
                                                const float* __restrict__ bias,
                                                float* __restrict__ C,
                                                int MN, int N, int nsk) {
  int i = (blockIdx.x * 256 + threadIdx.x) * 4;
  if (i >= MN) return;
  float4 s = make_float4(0.f, 0.f, 0.f, 0.f);
  if (bias) s = *(const float4*)&bias[i % N];
  for (int sk = 0; sk < nsk; ++sk) {
    float4 p = *(const float4*)&Cp[(size_t)sk * MN + i];
    s.x += p.x; s.y += p.y; s.z += p.z; s.w += p.w;
  }
  *(float4*)&C[i] = s;
}

// ---------------------------------------------------------------------------
// h[g,n,c] = he[g,c] + sum_f x_node[g,n,f] * Wg[f,c]   -> stored bf16
// ---------------------------------------------------------------------------
__global__ __launch_bounds__(256) void node_h_k(const float* __restrict__ xn,
                                                const float* __restrict__ Wg,
                                                const float* __restrict__ he,
                                                bf16* __restrict__ hbuf) {
  __shared__ float xns[64][32];
  __shared__ float wgs[32][256];
  const int cq = blockIdx.x, g = blockIdx.y;
  const int tid = threadIdx.x;
  for (int idx = tid; idx < 2048; idx += 256) xns[idx >> 5][idx & 31] = xn[g * 2048 + idx];
  for (int r = 0; r < 32; ++r) wgs[r][tid] = Wg[r * 1024 + cq * 256 + tid];
  __syncthreads();
  const float hev = he[g * 1024 + cq * 256 + tid];
  for (int n0 = 0; n0 < 64; n0 += 8) {
    float acc[8];
#pragma unroll
    for (int nn = 0; nn < 8; ++nn) acc[nn] = hev;
    for (int f = 0; f < 32; ++f) {
      float w = wgs[f][tid];
#pragma unroll
      for (int nn = 0; nn < 8; ++nn) acc[nn] += xns[n0 + nn][f] * w;
    }
#pragma unroll
    for (int nn = 0; nn < 8; ++nn)
      hbuf[(size_t)(g * 64 + n0 + nn) * 1024 + cq * 256 + tid] = __float2bfloat16(acc[nn]);
  }
}

// ---------------------------------------------------------------------------
// a_s[row,hd] = sum_e h[row, hd*256+e] * att_src[hd,e]; same for a_d.
// ---------------------------------------------------------------------------
__global__ __launch_bounds__(256) void as_ad_k(const bf16* __restrict__ hbuf,
                                               const float* __restrict__ att_s,
                                               const float* __restrict__ att_d,
                                               float* __restrict__ as_o,
                                               float* __restrict__ ad_o) {
  const int tid = threadIdx.x;
  const int lane = tid & 63, wv = tid >> 6;
  const int row = blockIdx.x * 4 + wv;
  const int hd = lane >> 4;
  const int e0 = (lane & 15) * 16;
  float as_r[16], ad_r[16];
#pragma unroll
  for (int q = 0; q < 4; ++q) {
    float4 v = *(const float4*)(att_s + hd * 256 + e0 + q * 4);
    as_r[q * 4 + 0] = v.x; as_r[q * 4 + 1] = v.y; as_r[q * 4 + 2] = v.z; as_r[q * 4 + 3] = v.w;
    float4 w = *(const float4*)(att_d + hd * 256 + e0 + q * 4);
    ad_r[q * 4 + 0] = w.x; ad_r[q * 4 + 1] = w.y; ad_r[q * 4 + 2] = w.z; ad_r[q * 4 + 3] = w.w;
  }
  const uint4* hp = (const uint4*)(hbuf + (size_t)row * 1024 + lane * 16);
  uint4 p0 = hp[0], p1 = hp[1];
  float hv[16];
  unp2(p0.x, hv[0], hv[1]);  unp2(p0.y, hv[2], hv[3]);
  unp2(p0.z, hv[4], hv[5]);  unp2(p0.w, hv[6], hv[7]);
  unp2(p1.x, hv[8], hv[9]);  unp2(p1.y, hv[10], hv[11]);
  unp2(p1.z, hv[12], hv[13]); unp2(p1.w, hv[14], hv[15]);
  float ps = 0.f, pd = 0.f;
#pragma unroll
  for (int i = 0; i < 16; ++i) { ps += as_r[i] * hv[i]; pd += ad_r[i] * hv[i]; }
#pragma unroll
  for (int m = 1; m < 16; m <<= 1) { ps += __shfl_xor(ps, m); pd += __shfl_xor(pd, m); }
  if ((lane & 15) == 0) { as_o[row * 4 + hd] = ps; ad_o[row * 4 + hd] = pd; }
}

// ---------------------------------------------------------------------------
// Per graph g: softmax over sources + head-mean aggregation + bias + relu.
// ---------------------------------------------------------------------------
__global__ __launch_bounds__(256) void attn_agg_k(const bf16* __restrict__ hbuf,
                                                  const float* __restrict__ as_i,
                                                  const float* __restrict__ ad_i,
                                                  const float* __restrict__ bgat,
                                                  __bf16* __restrict__ seq) {
  __shared__ float ass[256], ads[256], bgs[256];
  __shared__ float alpha[4][64][64];   // [hd][j][i]
  __shared__ float hq[64][260];        // one head-quarter of h, fp32
  const int g = blockIdx.x, tid = threadIdx.x;
  ass[tid] = as_i[g * 256 + tid];
  ads[tid] = ad_i[g * 256 + tid];
  bgs[tid] = bgat[tid];
  __syncthreads();
  {
    const int hd = tid >> 6, i = tid & 63;
    const float ad = ads[i * 4 + hd];
    float m = -1e30f;
    for (int j = 0; j < 64; ++j) {
      float s = ad + ass[j * 4 + hd];
      s = s > 0.0f ? s : 0.2f * s;
      m = fmaxf(m, s);
    }
    float sum = 0.0f;
    for (int j = 0; j < 64; ++j) {
      float s = ad + ass[j * 4 + hd];
      s = s > 0.0f ? s : 0.2f * s;
      sum += __expf(s - m);
    }
    const float inv = 1.0f / sum;
    for (int j = 0; j < 64; ++j) {
      float s = ad + ass[j * 4 + hd];
      s = s > 0.0f ? s : 0.2f * s;
      alpha[hd][j][i] = __expf(s - m) * inv;
    }
  }
  const int i = tid & 63, eq = tid >> 6;
  float acc[64] = {};
  for (int hd = 0; hd < 4; ++hd) {
    __syncthreads();
    for (int idx = tid; idx < 2048; idx += 256) {
      int j = idx >> 5, ch = idx & 31;
      uint4 p = *(const uint4*)(hbuf + (size_t)(g * 64 + j) * 1024 + hd * 256 + ch * 8);
      float f0, f1, f2, f3, f4, f5, f6, f7;
      unp2(p.x, f0, f1); unp2(p.y, f2, f3); unp2(p.z, f4, f5); unp2(p.w, f6, f7);
      *(float4*)&hq[j][ch * 8] = make_float4(f0, f1, f2, f3);
      *(float4*)&hq[j][ch * 8 + 4] = make_float4(f4, f5, f6, f7);
    }
    __syncthreads();
    for (int j = 0; j < 64; ++j) {
      const float a = alpha[hd][j][i];
      const float* hr = &hq[j][eq * 64];
#pragma unroll
      for (int q = 0; q < 16; ++q) {
        float4 hv = *(const float4*)(hr + q * 4);
        acc[q * 4 + 0] += a * hv.x; acc[q * 4 + 1] += a * hv.y;
        acc[q * 4 + 2] += a * hv.z; acc[q * 4 + 3] += a * hv.w;
      }
    }
  }
  __bf16* op = seq + (size_t)g * 16384 + i * 256 + eq * 64;
#pragma unroll
  for (int q = 0; q < 8; ++q) {
    float4 lo, hi;
    lo.x = fmaxf(bgs[eq * 64 + q * 8 + 0] + 0.25f * acc[q * 8 + 0], 0.0f);
    lo.y = fmaxf(bgs[eq * 64 + q * 8 + 1] + 0.25f * acc[q * 8 + 1], 0.0f);
    lo.z = fmaxf(bgs[eq * 64 + q * 8 + 2] + 0.25f * acc[q * 8 + 2], 0.0f);
    lo.w = fmaxf(bgs[eq * 64 + q * 8 + 3] + 0.25f * acc[q * 8 + 3], 0.0f);
    hi.x = fmaxf(bgs[eq * 64 + q * 8 + 4] + 0.25f * acc[q * 8 + 4], 0.0f);
    hi.y = fmaxf(bgs[eq * 64 + q * 8 + 5] + 0.25f * acc[q * 8 + 5], 0.0f);
    hi.z = fmaxf(bgs[eq * 64 + q * 8 + 6] + 0.25f * acc[q * 8 + 6], 0.0f);
    hi.w = fmaxf(bgs[eq * 64 + q * 8 + 7] + 0.25f * acc[q * 8 + 7], 0.0f);
    *(bf16x8*)(op + q * 8) = cvt8(lo, hi);
  }
}

// ---------------------------------------------------------------------------
// out[b,o] = b_fc[o] + sum_k y1[b,31,k] * Wfc[k,o]
// ---------------------------------------------------------------------------
__global__ __launch_bounds__(256) void fc_k(const float* __restrict__ y1,
                                            const float* __restrict__ Wfc,
                                            const float* __restrict__ bfc,
                                            float* __restrict__ out) {
  __shared__ float As[8][1024];
  const int tid = threadIdx.x;
  for (int idx = tid; idx < 8192; idx += 256) {
    int b = idx >> 10, k = idx & 1023;
    As[b][k] = y1[(size_t)(b * 32 + 31) * 1024 + k];
  }
  __syncthreads();
  const int ol = tid >> 2, kq = tid & 3;
  const int o = blockIdx.x * 64 + ol;
  float acc[8] = {};
  if (o < 2016) {
    for (int i2 = 0; i2 < 256; ++i2) {
      int k = i2 * 4 + kq;
      float w = Wfc[(size_t)k * 2016 + o];
#pragma unroll
      for (int b = 0; b < 8; ++b) acc[b] += As[b][k] * w;
    }
  }
#pragma unroll
  for (int b = 0; b < 8; ++b) {
    acc[b] += __shfl_xor(acc[b], 1);
    acc[b] += __shfl_xor(acc[b], 2);
  }
  if (kq == 0 && o < 2016) {
#pragma unroll
    for (int b = 0; b < 8; ++b) out[b * 2016 + o] = acc[b] + bfc[o];
  }
}

// ---------------------------------------------------------------------------
extern "C" void kernel_launch(void* const* d_in, const int* in_sizes, int n_in,
                              void* d_out, int out_size, void* d_ws, size_t ws_size,
                              hipStream_t stream) {
  (void)in_sizes; (void)n_in; (void)out_size; (void)ws_size;
  const float* x_node = (const float*)d_in[0];
  const float* x_edge = (const float*)d_in[1];
  // d_in[2] = edge_index: complete graph + self loops -> dense; unused.
  const float* W_gat = (const float*)d_in[3];
  const float* att_s = (const float*)d_in[4];
  const float* att_d = (const float*)d_in[5];
  const float* b_gat = (const float*)d_in[6];
  const float* W_ih0 = (const float*)d_in[7];
  const float* W_hh0 = (const float*)d_in[8];
  const float* b_ih0 = (const float*)d_in[9];
  const float* b_hh0 = (const float*)d_in[10];
  const float* W_ih1 = (const float*)d_in[11];
  const float* W_hh1 = (const float*)d_in[12];
  const float* b_ih1 = (const float*)d_in[13];
  const float* b_hh1 = (const float*)d_in[14];
  const float* W_fc  = (const float*)d_in[15];
  const float* b_fc  = (const float*)d_in[16];

  char* ws = (char*)d_ws;
  size_t off = 0;
  float*  he  = (float*)(ws + off);  off += 256u * 1024 * 4;           // 1 MB
  float*  a_s = (float*)(ws + off);  off += 256u * 64 * 4 * 4;         // 256 KB
  float*  a_d = (float*)(ws + off);  off += 256u * 64 * 4 * 4;         // 256 KB
  bf16*   hb  = (bf16*)(ws + off);   off += 256u * 64 * 1024 * 2;      // 32 MB
  __bf16* seq = (__bf16*)(ws + off); off += 256u * 16384 * 2;          // 8 MB
  float*  X0  = (float*)(ws + off);  off += 256u * 3072 * 4;           // 3 MB
  float*  y0  = (float*)(ws + off);  off += 256u * 1024 * 4;           // 1 MB
  float*  y1  = (float*)(ws + off);  off += 256u * 1024 * 4;           // 1 MB
  off = (off + 255) & ~(size_t)255;
  float*  Cp  = (float*)(ws + off);  off += (size_t)16 * 256 * 3072 * 4; // 48 MB

  // 1) he = x_edge @ W_gat[32:, :]   (M=256, N=1024, K=2016, B is [K,N]) SK=8
  mfma_gemm_k<false><<<dim3(8, 2, 8), 256, 0, stream>>>(
      x_edge, W_gat + 32 * 1024, Cp, 256, 1024, 2016, 2016, 1024, 8);
  reduce_k<<<256, 256, 0, stream>>>(Cp, nullptr, he, 256 * 1024, 1024, 8);
  // 2) h = node-proj + he (bf16)
  node_h_k<<<dim3(4, 256), 256, 0, stream>>>(x_node, W_gat, he, hb);
  // 3) attention logits
  as_ad_k<<<4096, 256, 0, stream>>>(hb, att_s, att_d, a_s, a_d);
  // 4) softmax + aggregation + relu -> seq [256, 16384] bf16
  attn_agg_k<<<256, 256, 0, stream>>>(hb, a_s, a_d, b_gat, seq);
  // 5) X0 = seq @ W_ih0^T + b_ih0   (M=256 full-tile, N=3072, K=16384) SK=16
  gemm_bt16_k<<<dim3(24, 1, 16), 256, 0, stream>>>(seq, W_ih0, Cp,
                                                   3072, 16384, 32);
  reduce_k<<<768, 256, 0, stream>>>(Cp, b_ih0, X0, 256 * 3072, 3072, 16);
  // 6+7+8) Both GRU layers, software-pipelined: launch t does layer0 step t
  //        and layer1 step t-1 (with fused fp32 input projection for layer 1).
  for (int t = 0; t <= 32; ++t)
    gru_fused_k<<<512, 256, 0, stream>>>(X0, W_hh0, b_hh0, y0,
                                         W_ih1, b_ih1, W_hh1, b_hh1, y1, t);
  // 9) out = y1[:, 31] @ W_fc + b_fc
  fc_k<<<32, 256, 0, stream>>>(y1, W_fc, b_fc, (float*)d_out);
}

// Round 10
// 697.974 us; speedup vs baseline: 1.2210x; 1.0966x over previous
//
#include <hip/hip_runtime.h>
#include <hip/hip_bf16.h>

using bf16 = __hip_bfloat16;
typedef __bf16 bf16x8 __attribute__((ext_vector_type(8)));
typedef float f32x4 __attribute__((ext_vector_type(4)));

// Sizes (fixed): B=8 S=32 N=64 F_NODE=32 TRI=2016 DIN=2048 H=4 DOUT=256 R=1024
// OUT=2016, G=B*S=256 graphs

__device__ __forceinline__ void unp2(unsigned int u, float& a, float& b) {
  a = __uint_as_float(u << 16);
  b = __uint_as_float(u & 0xffff0000u);
}

__device__ __forceinline__ bf16x8 cvt8(float4 a, float4 b) {
  bf16x8 r;
  r[0] = (__bf16)a.x; r[1] = (__bf16)a.y; r[2] = (__bf16)a.z; r[3] = (__bf16)a.w;
  r[4] = (__bf16)b.x; r[5] = (__bf16)b.y; r[6] = (__bf16)b.z; r[7] = (__bf16)b.w;
  return r;
}

// ---------------------------------------------------------------------------
// One GRU step, occupancy-tuned.  512 blocks x 256 threads, 2 blocks/CU
// (2 waves/SIMD).  Block (jg = bid>>1, bh = bid&1) owns 4 j's (one wave per
// j) x 4 batches (bh half).  W_hh from global: 48 KB/block slice, read by 2
// blocks -> 3 MB/XCD in L2, warm across the 32 step launches.
// Lane = (bl = lane>>4: batch, kg = lane&15: K-sixteenth); W addresses are
// identical across bl groups (wave fetches one contiguous 256 B per f4 step).
// ---------------------------------------------------------------------------
__global__ __launch_bounds__(256) void gru_step3_k(
    const float* __restrict__ X,    // [256, 3072] gi
    const float* __restrict__ Whh,  // [3072, 1024]
    const float* __restrict__ bhh,  // [3072]
    float* __restrict__ y,          // [256, 1024]
    int s, int first) {
  __shared__ float hs[4][1028];     // pad 4: spreads bl groups across banks
  const int tid = threadIdx.x;
  const int bh = blockIdx.x & 1;
  const int jg = blockIdx.x >> 1;
  if (first) {
#pragma unroll
    for (int q = 0; q < 4; ++q) {
      int idx = q * 256 + tid;
      *(float4*)&hs[idx >> 8][(idx & 255) * 4] = make_float4(0.f, 0.f, 0.f, 0.f);
    }
  } else {
#pragma unroll
    for (int q = 0; q < 4; ++q) {
      int idx = q * 256 + tid;
      int bl = idx >> 8, kf = (idx & 255) * 4;
      *(float4*)&hs[bl][kf] =
          *(const float4*)&y[(size_t)((bh * 4 + bl) * 32 + s - 1) * 1024 + kf];
    }
  }
  __syncthreads();
  const int wv = tid >> 6, lane = tid & 63;
  const int j = jg * 4 + wv;
  const int bl = lane >> 4, kg = lane & 15;
  const float* Wr = Whh + (size_t)j * 1024;
  const float* Wz = Whh + (size_t)(1024 + j) * 1024;
  const float* Wn = Whh + (size_t)(2048 + j) * 1024;
  float aR = 0.f, aZ = 0.f, aN = 0.f;
#pragma unroll
  for (int q = 0; q < 16; ++q) {
    const int k = q * 64 + kg * 4;       // 16 lanes contiguous 256 B
    float4 wr = *(const float4*)&Wr[k];
    float4 wz = *(const float4*)&Wz[k];
    float4 wn = *(const float4*)&Wn[k];
    float4 h4 = *(const float4*)&hs[bl][k];
    aR += h4.x * wr.x + h4.y * wr.y + h4.z * wr.z + h4.w * wr.w;
    aZ += h4.x * wz.x + h4.y * wz.y + h4.z * wz.z + h4.w * wz.w;
    aN += h4.x * wn.x + h4.y * wn.y + h4.z * wn.z + h4.w * wn.w;
  }
#pragma unroll
  for (int d = 1; d < 16; d <<= 1) {     // reduce across kg (lane bits 0..3)
    aR += __shfl_xor(aR, d);
    aZ += __shfl_xor(aZ, d);
    aN += __shfl_xor(aN, d);
  }
  if (kg == 0) {
    const int b = bh * 4 + bl;
    const float* gip = X + (size_t)(b * 32 + s) * 3072;
    float r = 1.0f / (1.0f + __expf(-(gip[j] + aR + bhh[j])));
    float z = 1.0f / (1.0f + __expf(-(gip[1024 + j] + aZ + bhh[1024 + j])));
    float n = tanhf(gip[2048 + j] + r * (aN + bhh[2048 + j]));
    float hp = hs[bl][j];
    y[(size_t)(b * 32 + s) * 1024 + j] = (1.0f - z) * n + z * hp;
  }
}

// ---------------------------------------------------------------------------
// X0 GEMM: Cp[z][m][n] = sum_{k in chunk z} A[m,k]*B[n,k]
// A: [256, K] bf16.  B: [N, K] fp32.  M-tile 256 (full M), N-tile 128, BK=32.
// SK=32 -> 768 blocks (3/CU) to raise memory-level parallelism.
// ---------------------------------------------------------------------------
__global__ __launch_bounds__(256) void gemm_bt16_k(const __bf16* __restrict__ A,
                                                   const float* __restrict__ Bm,
                                                   float* __restrict__ Cp,
                                                   int N, int K, int ksper) {
  __shared__ __bf16 As[256][40];   // 80B row stride: aligned, ~2-way bank alias
  __shared__ __bf16 Bs[128][40];
  const int tid = threadIdx.x;
  const int bn = blockIdx.x * 128;
  const int lane = tid & 63, wv = tid >> 6;
  const int wr = wv >> 1, wc = wv & 1;
  const int lr = lane & 15, kh = lane >> 4;
  const int brow = tid >> 1, bhalf = tid & 1;
  f32x4 acc[8][4] = {};
  const int kstot = K >> 5;
  int ks0 = blockIdx.z * ksper;
  int ks1 = ks0 + ksper; if (ks1 > kstot) ks1 = kstot;
  uint4 ra0, ra1, ra2, ra3; float4 rb0, rb1, rb2, rb3;
  {
    const int k0 = ks0 << 5;
    const uint4* ap = (const uint4*)(A + (size_t)tid * K + k0);
    ra0 = ap[0]; ra1 = ap[1]; ra2 = ap[2]; ra3 = ap[3];
    const float* bp = Bm + (size_t)(bn + brow) * K + k0 + bhalf * 16;
    rb0 = ((const float4*)bp)[0]; rb1 = ((const float4*)bp)[1];
    rb2 = ((const float4*)bp)[2]; rb3 = ((const float4*)bp)[3];
  }
  for (int ks = ks0; ks < ks1; ++ks) {
    __syncthreads();
    *(uint4*)&As[tid][0]  = ra0;
    *(uint4*)&As[tid][8]  = ra1;
    *(uint4*)&As[tid][16] = ra2;
    *(uint4*)&As[tid][24] = ra3;
    *(bf16x8*)&Bs[brow][bhalf * 16] = cvt8(rb0, rb1);
    *(bf16x8*)&Bs[brow][bhalf * 16 + 8] = cvt8(rb2, rb3);
    __syncthreads();
    if (ks + 1 < ks1) {  // prefetch next K-tile into regs; overlaps with MFMA
      const int k0 = (ks + 1) << 5;
      const uint4* ap = (const uint4*)(A + (size_t)tid * K + k0);
      ra0 = ap[0]; ra1 = ap[1]; ra2 = ap[2]; ra3 = ap[3];
      const float* bp = Bm + (size_t)(bn + brow) * K + k0 + bhalf * 16;
      rb0 = ((const float4*)bp)[0]; rb1 = ((const float4*)bp)[1];
      rb2 = ((const float4*)bp)[2]; rb3 = ((const float4*)bp)[3];
    }
    bf16x8 bfv[4];
#pragma unroll
    for (int ni = 0; ni < 4; ++ni)
      bfv[ni] = *(const bf16x8*)&Bs[wc * 64 + ni * 16 + lr][kh * 8];
#pragma unroll
    for (int mi = 0; mi < 8; ++mi) {
      bf16x8 af = *(const bf16x8*)&As[wr * 128 + mi * 16 + lr][kh * 8];
#pragma unroll
      for (int ni = 0; ni < 4; ++ni)
        acc[mi][ni] = __builtin_amdgcn_mfma_f32_16x16x32_bf16(af, bfv[ni],
                                                              acc[mi][ni], 0, 0, 0);
    }
  }
  float* cp = Cp + (size_t)blockIdx.z * 256 * N;
#pragma unroll
  for (int mi = 0; mi < 8; ++mi) {
#pragma unroll
    for (int ni = 0; ni < 4; ++ni) {
      const int row = wr * 128 + mi * 16 + kh * 4;
      const int col = bn + wc * 64 + ni * 16 + lr;
#pragma unroll
      for (int j = 0; j < 4; ++j)
        cp[(size_t)(row + j) * N + col] = acc[mi][ni][j];
    }
  }
}

// ---------------------------------------------------------------------------
// fp32-input MFMA GEMM (he: B [K,N]; X1: B [N,K]) with split-K.
// ---------------------------------------------------------------------------
template <bool BT>
__global__ __launch_bounds__(256) void mfma_gemm_k(const float* __restrict__ A,
                                                   const float* __restrict__ Bm,
                                                   float* __restrict__ Cp,
                                                   int M, int N, int K,
                                                   int lda, int ldb, int ksper) {
  __shared__ __bf16 As[128][40];
  __shared__ __bf16 Bs[128][40];
  const int tid = threadIdx.x;
  const int bm = blockIdx.y * 128, bn = blockIdx.x * 128;
  const int lane = tid & 63, wv = tid >> 6;
  const int wr = wv >> 1, wc = wv & 1;
  const int lr = lane & 15, kh = lane >> 4;
  f32x4 acc[4][4] = {};
  const int kstot = K >> 5;
  int ks0 = blockIdx.z * ksper;
  int ks1 = ks0 + ksper; if (ks1 > kstot) ks1 = kstot;
  for (int ks = ks0; ks < ks1; ++ks) {
    const int k0 = ks << 5;
    __syncthreads();
    {
      const int row = tid >> 1, half = tid & 1;
      const float* ap = A + (size_t)(bm + row) * lda + k0 + half * 16;
      float4 f0 = ((const float4*)ap)[0], f1 = ((const float4*)ap)[1];
      float4 f2 = ((const float4*)ap)[2], f3 = ((const float4*)ap)[3];
      *(bf16x8*)&As[row][half * 16] = cvt8(f0, f1);
      *(bf16x8*)&As[row][half * 16 + 8] = cvt8(f2, f3);
    }
    if (BT) {
      const int row = tid >> 1, half = tid & 1;
      const float* bp = Bm + (size_t)(bn + row) * ldb + k0 + half * 16;
      float4 f0 = ((const float4*)bp)[0], f1 = ((const float4*)bp)[1];
      float4 f2 = ((const float4*)bp)[2], f3 = ((const float4*)bp)[3];
      *(bf16x8*)&Bs[row][half * 16] = cvt8(f0, f1);
      *(bf16x8*)&Bs[row][half * 16 + 8] = cvt8(f2, f3);
    } else {
      const int kk = tid >> 3, ng = tid & 7;
      const float* bp = Bm + (size_t)(k0 + kk) * ldb + bn + ng * 16;
      float4 f[4];
#pragma unroll
      for (int q = 0; q < 4; ++q) f[q] = ((const float4*)bp)[q];
#pragma unroll
      for (int q = 0; q < 4; ++q) {
        Bs[ng * 16 + q * 4 + 0][kk] = (__bf16)f[q].x;
        Bs[ng * 16 + q * 4 + 1][kk] = (__bf16)f[q].y;
        Bs[ng * 16 + q * 4 + 2][kk] = (__bf16)f[q].z;
        Bs[ng * 16 + q * 4 + 3][kk] = (__bf16)f[q].w;
      }
    }
    __syncthreads();
    bf16x8 af[4], bfv[4];
#pragma unroll
    for (int mi = 0; mi < 4; ++mi)
      af[mi] = *(const bf16x8*)&As[wr * 64 + mi * 16 + lr][kh * 8];
#pragma unroll
    for (int ni = 0; ni < 4; ++ni)
      bfv[ni] = *(const bf16x8*)&Bs[wc * 64 + ni * 16 + lr][kh * 8];
#pragma unroll
    for (int mi = 0; mi < 4; ++mi)
#pragma unroll
      for (int ni = 0; ni < 4; ++ni)
        acc[mi][ni] = __builtin_amdgcn_mfma_f32_16x16x32_bf16(af[mi], bfv[ni],
                                                              acc[mi][ni], 0, 0, 0);
  }
  float* cp = Cp + (size_t)blockIdx.z * M * N;
#pragma unroll
  for (int mi = 0; mi < 4; ++mi) {
#pragma unroll
    for (int ni = 0; ni < 4; ++ni) {
      const int row = bm + wr * 64 + mi * 16 + kh * 4;
      const int col = bn + wc * 64 + ni * 16 + lr;
#pragma unroll
      for (int j = 0; j < 4; ++j)
        cp[(size_t)(row + j) * N + col] = acc[mi][ni][j];
    }
  }
}

// C[i] = bias[i%N] + sum_sk Cp[sk][i]
__global__ __launch_bounds__(256) void reduce_k(const float* __restrict__ Cp,
                                                const float* __restrict__ bias,
                                                float* __restrict__ C,
                                                int MN, int N, int nsk) {
  int i = (blockIdx.x * 256 + threadIdx.x) * 4;
  if (i >= MN) return;
  float4 s = make_float4(0.f, 0.f, 0.f, 0.f);
  if (bias) s = *(const float4*)&bias[i % N];
  for (int sk = 0; sk < nsk; ++sk) {
    float4 p = *(const float4*)&Cp[(size_t)sk * MN + i];
    s.x += p.x; s.y += p.y; s.z += p.z; s.w += p.w;
  }
  *(float4*)&C[i] = s;
}

// ---------------------------------------------------------------------------
// h[g,n,c] = he[g,c] + sum_f x_node[g,n,f] * Wg[f,c]   -> stored bf16
// ---------------------------------------------------------------------------
__global__ __launch_bounds__(256) void node_h_k(const float* __restrict__ xn,
                                                const float* __restrict__ Wg,
                                                const float* __restrict__ he,
                                                bf16* __restrict__ hbuf) {
  __shared__ float xns[64][32];
  __shared__ float wgs[32][256];
  const int cq = blockIdx.x, g = blockIdx.y;
  const int tid = threadIdx.x;
  for (int idx = tid; idx < 2048; idx += 256) xns[idx >> 5][idx & 31] = xn[g * 2048 + idx];
  for (int r = 0; r < 32; ++r) wgs[r][tid] = Wg[r * 1024 + cq * 256 + tid];
  __syncthreads();
  const float hev = he[g * 1024 + cq * 256 + tid];
  for (int n0 = 0; n0 < 64; n0 += 8) {
    float acc[8];
#pragma unroll
    for (int nn = 0; nn < 8; ++nn) acc[nn] = hev;
    for (int f = 0; f < 32; ++f) {
      float w = wgs[f][tid];
#pragma unroll
      for (int nn = 0; nn < 8; ++nn) acc[nn] += xns[n0 + nn][f] * w;
    }
#pragma unroll
    for (int nn = 0; nn < 8; ++nn)
      hbuf[(size_t)(g * 64 + n0 + nn) * 1024 + cq * 256 + tid] = __float2bfloat16(acc[nn]);
  }
}

// ---------------------------------------------------------------------------
// a_s[row,hd] = sum_e h[row, hd*256+e] * att_src[hd,e]; same for a_d.
// ---------------------------------------------------------------------------
__global__ __launch_bounds__(256) void as_ad_k(const bf16* __restrict__ hbuf,
                                               const float* __restrict__ att_s,
                                               const float* __restrict__ att_d,
                                               float* __restrict__ as_o,
                                               float* __restrict__ ad_o) {
  const int tid = threadIdx.x;
  const int lane = tid & 63, wv = tid >> 6;
  const int row = blockIdx.x * 4 + wv;
  const int hd = lane >> 4;
  const int e0 = (lane & 15) * 16;
  float as_r[16], ad_r[16];
#pragma unroll
  for (int q = 0; q < 4; ++q) {
    float4 v = *(const float4*)(att_s + hd * 256 + e0 + q * 4);
    as_r[q * 4 + 0] = v.x; as_r[q * 4 + 1] = v.y; as_r[q * 4 + 2] = v.z; as_r[q * 4 + 3] = v.w;
    float4 w = *(const float4*)(att_d + hd * 256 + e0 + q * 4);
    ad_r[q * 4 + 0] = w.x; ad_r[q * 4 + 1] = w.y; ad_r[q * 4 + 2] = w.z; ad_r[q * 4 + 3] = w.w;
  }
  const uint4* hp = (const uint4*)(hbuf + (size_t)row * 1024 + lane * 16);
  uint4 p0 = hp[0], p1 = hp[1];
  float hv[16];
  unp2(p0.x, hv[0], hv[1]);  unp2(p0.y, hv[2], hv[3]);
  unp2(p0.z, hv[4], hv[5]);  unp2(p0.w, hv[6], hv[7]);
  unp2(p1.x, hv[8], hv[9]);  unp2(p1.y, hv[10], hv[11]);
  unp2(p1.z, hv[12], hv[13]); unp2(p1.w, hv[14], hv[15]);
  float ps = 0.f, pd = 0.f;
#pragma unroll
  for (int i = 0; i < 16; ++i) { ps += as_r[i] * hv[i]; pd += ad_r[i] * hv[i]; }
#pragma unroll
  for (int m = 1; m < 16; m <<= 1) { ps += __shfl_xor(ps, m); pd += __shfl_xor(pd, m); }
  if ((lane & 15) == 0) { as_o[row * 4 + hd] = ps; ad_o[row * 4 + hd] = pd; }
}

// ---------------------------------------------------------------------------
// Per graph g: softmax over sources + head-mean aggregation + bias + relu.
// ---------------------------------------------------------------------------
__global__ __launch_bounds__(256) void attn_agg_k(const bf16* __restrict__ hbuf,
                                                  const float* __restrict__ as_i,
                                                  const float* __restrict__ ad_i,
                                                  const float* __restrict__ bgat,
                                                  __bf16* __restrict__ seq) {
  __shared__ float ass[256], ads[256], bgs[256];
  __shared__ float alpha[4][64][64];   // [hd][j][i]
  __shared__ float hq[64][260];        // one head-quarter of h, fp32
  const int g = blockIdx.x, tid = threadIdx.x;
  ass[tid] = as_i[g * 256 + tid];
  ads[tid] = ad_i[g * 256 + tid];
  bgs[tid] = bgat[tid];
  __syncthreads();
  {
    const int hd = tid >> 6, i = tid & 63;
    const float ad = ads[i * 4 + hd];
    float m = -1e30f;
    for (int j = 0; j < 64; ++j) {
      float s = ad + ass[j * 4 + hd];
      s = s > 0.0f ? s : 0.2f * s;
      m = fmaxf(m, s);
    }
    float sum = 0.0f;
    for (int j = 0; j < 64; ++j) {
      float s = ad + ass[j * 4 + hd];
      s = s > 0.0f ? s : 0.2f * s;
      sum += __expf(s - m);
    }
    const float inv = 1.0f / sum;
    for (int j = 0; j < 64; ++j) {
      float s = ad + ass[j * 4 + hd];
      s = s > 0.0f ? s : 0.2f * s;
      alpha[hd][j][i] = __expf(s - m) * inv;
    }
  }
  const int i = tid & 63, eq = tid >> 6;
  float acc[64] = {};
  for (int hd = 0; hd < 4; ++hd) {
    __syncthreads();
    for (int idx = tid; idx < 2048; idx += 256) {
      int j = idx >> 5, ch = idx & 31;
      uint4 p = *(const uint4*)(hbuf + (size_t)(g * 64 + j) * 1024 + hd * 256 + ch * 8);
      float f0, f1, f2, f3, f4, f5, f6, f7;
      unp2(p.x, f0, f1); unp2(p.y, f2, f3); unp2(p.z, f4, f5); unp2(p.w, f6, f7);
      *(float4*)&hq[j][ch * 8] = make_float4(f0, f1, f2, f3);
      *(float4*)&hq[j][ch * 8 + 4] = make_float4(f4, f5, f6, f7);
    }
    __syncthreads();
    for (int j = 0; j < 64; ++j) {
      const float a = alpha[hd][j][i];
      const float* hr = &hq[j][eq * 64];
#pragma unroll
      for (int q = 0; q < 16; ++q) {
        float4 hv = *(const float4*)(hr + q * 4);
        acc[q * 4 + 0] += a * hv.x; acc[q * 4 + 1] += a * hv.y;
        acc[q * 4 + 2] += a * hv.z; acc[q * 4 + 3] += a * hv.w;
      }
    }
  }
  __bf16* op = seq + (size_t)g * 16384 + i * 256 + eq * 64;
#pragma unroll
  for (int q = 0; q < 8; ++q) {
    float4 lo, hi;
    lo.x = fmaxf(bgs[eq * 64 + q * 8 + 0] + 0.25f * acc[q * 8 + 0], 0.0f);
    lo.y = fmaxf(bgs[eq * 64 + q * 8 + 1] + 0.25f * acc[q * 8 + 1], 0.0f);
    lo.z = fmaxf(bgs[eq * 64 + q * 8 + 2] + 0.25f * acc[q * 8 + 2], 0.0f);
    lo.w = fmaxf(bgs[eq * 64 + q * 8 + 3] + 0.25f * acc[q * 8 + 3], 0.0f);
    hi.x = fmaxf(bgs[eq * 64 + q * 8 + 4] + 0.25f * acc[q * 8 + 4], 0.0f);
    hi.y = fmaxf(bgs[eq * 64 + q * 8 + 5] + 0.25f * acc[q * 8 + 5], 0.0f);
    hi.z = fmaxf(bgs[eq * 64 + q * 8 + 6] + 0.25f * acc[q * 8 + 6], 0.0f);
    hi.w = fmaxf(bgs[eq * 64 + q * 8 + 7] + 0.25f * acc[q * 8 + 7], 0.0f);
    *(bf16x8*)(op + q * 8) = cvt8(lo, hi);
  }
}

// ---------------------------------------------------------------------------
// out[b,o] = b_fc[o] + sum_k y1[b,31,k] * Wfc[k,o]
// ---------------------------------------------------------------------------
__global__ __launch_bounds__(256) void fc_k(const float* __restrict__ y1,
                                            const float* __restrict__ Wfc,
                                            const float* __restrict__ bfc,
                                            float* __restrict__ out) {
  __shared__ float As[8][1024];
  const int tid = threadIdx.x;
  for (int idx = tid; idx < 8192; idx += 256) {
    int b = idx >> 10, k = idx & 1023;
    As[b][k] = y1[(size_t)(b * 32 + 31) * 1024 + k];
  }
  __syncthreads();
  const int ol = tid >> 2, kq = tid & 3;
  const int o = blockIdx.x * 64 + ol;
  float acc[8] = {};
  if (o < 2016) {
    for (int i2 = 0; i2 < 256; ++i2) {
      int k = i2 * 4 + kq;
      float w = Wfc[(size_t)k * 2016 + o];
#pragma unroll
      for (int b = 0; b < 8; ++b) acc[b] += As[b][k] * w;
    }
  }
#pragma unroll
  for (int b = 0; b < 8; ++b) {
    acc[b] += __shfl_xor(acc[b], 1);
    acc[b] += __shfl_xor(acc[b], 2);
  }
  if (kq == 0 && o < 2016) {
#pragma unroll
    for (int b = 0; b < 8; ++b) out[b * 2016 + o] = acc[b] + bfc[o];
  }
}

// ---------------------------------------------------------------------------
extern "C" void kernel_launch(void* const* d_in, const int* in_sizes, int n_in,
                              void* d_out, int out_size, void* d_ws, size_t ws_size,
                              hipStream_t stream) {
  (void)in_sizes; (void)n_in; (void)out_size; (void)ws_size;
  const float* x_node = (const float*)d_in[0];
  const float* x_edge = (const float*)d_in[1];
  // d_in[2] = edge_index: complete graph + self loops -> dense; unused.
  const float* W_gat = (const float*)d_in[3];
  const float* att_s = (const float*)d_in[4];
  const float* att_d = (const float*)d_in[5];
  const float* b_gat = (const float*)d_in[6];
  const float* W_ih0 = (const float*)d_in[7];
  const float* W_hh0 = (const float*)d_in[8];
  const float* b_ih0 = (const float*)d_in[9];
  const float* b_hh0 = (const float*)d_in[10];
  const float* W_ih1 = (const float*)d_in[11];
  const float* W_hh1 = (const float*)d_in[12];
  const float* b_ih1 = (const float*)d_in[13];
  const float* b_hh1 = (const float*)d_in[14];
  const float* W_fc  = (const float*)d_in[15];
  const float* b_fc  = (const float*)d_in[16];

  char* ws = (char*)d_ws;
  size_t off = 0;
  float*  he  = (float*)(ws + off);  off += 256u * 1024 * 4;           // 1 MB
  float*  a_s = (float*)(ws + off);  off += 256u * 64 * 4 * 4;         // 256 KB
  float*  a_d = (float*)(ws + off);  off += 256u * 64 * 4 * 4;         // 256 KB
  bf16*   hb  = (bf16*)(ws + off);   off += 256u * 64 * 1024 * 2;      // 32 MB
  __bf16* seq = (__bf16*)(ws + off); off += 256u * 16384 * 2;          // 8 MB
  float*  X0  = (float*)(ws + off);  off += 256u * 3072 * 4;           // 3 MB
  float*  y0  = (float*)(ws + off);  off += 256u * 1024 * 4;           // 1 MB
  float*  X1  = (float*)(ws + off);  off += 256u * 3072 * 4;           // 3 MB
  float*  y1  = (float*)(ws + off);  off += 256u * 1024 * 4;           // 1 MB
  off = (off + 255) & ~(size_t)255;
  float*  Cp  = (float*)(ws + off);  off += (size_t)32 * 256 * 3072 * 4; // 96 MB

  // 1) he = x_edge @ W_gat[32:, :]   (M=256, N=1024, K=2016, B is [K,N]) SK=8
  mfma_gemm_k<false><<<dim3(8, 2, 8), 256, 0, stream>>>(
      x_edge, W_gat + 32 * 1024, Cp, 256, 1024, 2016, 2016, 1024, 8);
  reduce_k<<<256, 256, 0, stream>>>(Cp, nullptr, he, 256 * 1024, 1024, 8);
  // 2) h = node-proj + he (bf16)
  node_h_k<<<dim3(4, 256), 256, 0, stream>>>(x_node, W_gat, he, hb);
  // 3) attention logits
  as_ad_k<<<4096, 256, 0, stream>>>(hb, att_s, att_d, a_s, a_d);
  // 4) softmax + aggregation + relu -> seq [256, 16384] bf16
  attn_agg_k<<<256, 256, 0, stream>>>(hb, a_s, a_d, b_gat, seq);
  // 5) X0 = seq @ W_ih0^T + b_ih0   (M=256 full-tile, N=3072, K=16384) SK=32
  gemm_bt16_k<<<dim3(24, 1, 32), 256, 0, stream>>>(seq, W_ih0, Cp,
                                                   3072, 16384, 16);
  reduce_k<<<768, 256, 0, stream>>>(Cp, b_ih0, X0, 256 * 3072, 3072, 32);
  // 6) GRU layer 0: one lean launch per step (512 blocks, 2/CU)
  for (int s = 0; s < 32; ++s)
    gru_step3_k<<<512, 256, 0, stream>>>(X0, W_hh0, b_hh0, y0, s, s == 0 ? 1 : 0);
  // 7) X1 = y0 @ W_ih1^T + b_ih1    (M=256, N=3072, K=1024) SK=4
  mfma_gemm_k<true><<<dim3(24, 2, 4), 256, 0, stream>>>(
      y0, W_ih1, Cp, 256, 3072, 1024, 1024, 1024, 8);
  reduce_k<<<768, 256, 0, stream>>>(Cp, b_ih1, X1, 256 * 3072, 3072, 4);
  // 8) GRU layer 1
  for (int s = 0; s < 32; ++s)
    gru_step3_k<<<512, 256, 0, stream>>>(X1, W_hh1, b_hh1, y1, s, s == 0 ? 1 : 0);
  // 9) out = y1[:, 31] @ W_fc + b_fc
  fc_k<<<32, 256, 0, stream>>>(y1, W_fc, b_fc, (float*)d_out);
}

// Round 11
// 653.116 us; speedup vs baseline: 1.3049x; 1.0687x over previous
//
#include <hip/hip_runtime.h>
#include <hip/hip_bf16.h>

using bf16 = __hip_bfloat16;
typedef __bf16 bf16x8 __attribute__((ext_vector_type(8)));
typedef float f32x4 __attribute__((ext_vector_type(4)));

// Sizes (fixed): B=8 S=32 N=64 F_NODE=32 TRI=2016 DIN=2048 H=4 DOUT=256 R=1024
// OUT=2016, G=B*S=256 graphs

__device__ __forceinline__ void unp2(unsigned int u, float& a, float& b) {
  a = __uint_as_float(u << 16);
  b = __uint_as_float(u & 0xffff0000u);
}

__device__ __forceinline__ bf16x8 cvt8(float4 a, float4 b) {
  bf16x8 r;
  r[0] = (__bf16)a.x; r[1] = (__bf16)a.y; r[2] = (__bf16)a.z; r[3] = (__bf16)a.w;
  r[4] = (__bf16)b.x; r[5] = (__bf16)b.y; r[6] = (__bf16)b.z; r[7] = (__bf16)b.w;
  return r;
}

// ---------------------------------------------------------------------------
// One-shot fp32 -> bf16 conversion of the three RNN weight matrices.
// n = 3*1024*1024 elements each; grid 1536 x 256, 8 elems/thread/matrix.
// ---------------------------------------------------------------------------
__global__ __launch_bounds__(256) void wcvt_k(const float* __restrict__ a,
                                              const float* __restrict__ b,
                                              const float* __restrict__ c,
                                              __bf16* __restrict__ A,
                                              __bf16* __restrict__ B,
                                              __bf16* __restrict__ C) {
  const int i = (blockIdx.x * 256 + threadIdx.x) * 8;
  float4 x0 = *(const float4*)&a[i], x1 = *(const float4*)&a[i + 4];
  *(bf16x8*)&A[i] = cvt8(x0, x1);
  float4 y0_ = *(const float4*)&b[i], y1_ = *(const float4*)&b[i + 4];
  *(bf16x8*)&B[i] = cvt8(y0_, y1_);
  float4 z0 = *(const float4*)&c[i], z1 = *(const float4*)&c[i + 4];
  *(bf16x8*)&C[i] = cvt8(z0, z1);
}

// ---------------------------------------------------------------------------
// Fused two-layer GRU step, software-pipelined across 33 launches.
// Launch t (t = 0..32), grid 768 blocks (all co-resident, ~33 KB LDS):
//   blocks [0,256):   layer 0 step t   (skip t==32); 4 j's, one wave per j,
//                     bf16 W_hh0 rows from L2-warm global.
//   blocks [256,768): layer 1 step t-1 (skip t==0); 2 j's, wave = (j-pair p,
//                     role: 0 = x-side W_ih1 over sA=y0[t-1], 1 = h-side
//                     W_hh1 over y1[t-2] read direct from L2).  Balanced:
//                     every wave does 3 dots of K=1024 over 8 batches.
// Per-launch weight footprint 18 MB bf16 (2.25 MB/XCD) -> L2-resident.
// Cross-launch dataflow via global memory (kernel-boundary coherence).
// ---------------------------------------------------------------------------
__global__ __launch_bounds__(256) void gru_fused2_k(
    const float* __restrict__ X0,      // [256, 3072] layer-0 gi
    const __bf16* __restrict__ Wb0,    // [3072, 1024] bf16 W_hh0
    const float* __restrict__ bhh0,    // [3072]
    float* __restrict__ y0,            // [256, 1024]
    const __bf16* __restrict__ Wbi1,   // [3072, 1024] bf16 W_ih1
    const float* __restrict__ bih1,    // [3072]
    const __bf16* __restrict__ Wbh1,   // [3072, 1024] bf16 W_hh1
    const float* __restrict__ bhh1,    // [3072]
    float* __restrict__ y1,            // [256, 1024]
    int t) {
  __shared__ float sA[8][1024];        // 32 KB
  __shared__ float part[2][2][3][8];   // layer-1 partials [p][role][gate][b]
  const int tid = threadIdx.x;
  const int wv = tid >> 6, lane = tid & 63;

  if (blockIdx.x < 256) {
    // ------------------------- layer 0, step t -------------------------
    if (t >= 32) return;
    const int s = t;
    if (s == 0) {
#pragma unroll
      for (int q = 0; q < 8; ++q) {
        int idx = q * 256 + tid;
        *(float4*)&sA[idx >> 8][(idx & 255) * 4] = make_float4(0.f, 0.f, 0.f, 0.f);
      }
    } else {
#pragma unroll
      for (int q = 0; q < 8; ++q) {
        int idx = q * 256 + tid;
        int b = idx >> 8, kf = (idx & 255) * 4;
        *(float4*)&sA[b][kf] =
            *(const float4*)&y0[(size_t)(b * 32 + s - 1) * 1024 + kf];
      }
    }
    __syncthreads();
    const int j = blockIdx.x * 4 + wv;
    const __bf16* Wr = Wb0 + (size_t)j * 1024;
    const __bf16* Wz = Wb0 + (size_t)(1024 + j) * 1024;
    const __bf16* Wn = Wb0 + (size_t)(2048 + j) * 1024;
    float accR[8] = {}, accZ[8] = {}, accN[8] = {};
#pragma unroll
    for (int kk = 0; kk < 4; ++kk) {
      const int k = kk * 256 + lane * 4;   // 8B/lane bf16: wave = 512B contig
      uint2 uR = *(const uint2*)&Wr[k];
      uint2 uZ = *(const uint2*)&Wz[k];
      uint2 uN = *(const uint2*)&Wn[k];
      float r0, r1, r2, r3, z0, z1, z2, z3, n0, n1, n2, n3;
      unp2(uR.x, r0, r1); unp2(uR.y, r2, r3);
      unp2(uZ.x, z0, z1); unp2(uZ.y, z2, z3);
      unp2(uN.x, n0, n1); unp2(uN.y, n2, n3);
#pragma unroll
      for (int b = 0; b < 8; ++b) {
        float4 h4 = *(const float4*)&sA[b][k];
        accR[b] += h4.x * r0 + h4.y * r1 + h4.z * r2 + h4.w * r3;
        accZ[b] += h4.x * z0 + h4.y * z1 + h4.z * z2 + h4.w * z3;
        accN[b] += h4.x * n0 + h4.y * n1 + h4.z * n2 + h4.w * n3;
      }
    }
#pragma unroll
    for (int d = 1; d < 64; d <<= 1) {
#pragma unroll
      for (int b = 0; b < 8; ++b) {
        accR[b] += __shfl_xor(accR[b], d);
        accZ[b] += __shfl_xor(accZ[b], d);
        accN[b] += __shfl_xor(accN[b], d);
      }
    }
    if (lane < 8) {
      const int b = lane;
      float sr = 0.f, sz = 0.f, sn = 0.f;
#pragma unroll
      for (int bb = 0; bb < 8; ++bb)
        if (b == bb) { sr = accR[bb]; sz = accZ[bb]; sn = accN[bb]; }
      const float* gip = X0 + (size_t)(b * 32 + s) * 3072;
      float r = 1.0f / (1.0f + __expf(-(gip[j] + sr + bhh0[j])));
      float z = 1.0f / (1.0f + __expf(-(gip[1024 + j] + sz + bhh0[1024 + j])));
      float n = tanhf(gip[2048 + j] + r * (sn + bhh0[2048 + j]));
      float hp = sA[b][j];
      y0[(size_t)(b * 32 + s) * 1024 + j] = (1.0f - z) * n + z * hp;
    }
  } else {
    // ------------------------- layer 1, step t-1 -------------------------
    if (t < 1) return;
    const int s = t - 1;
#pragma unroll
    for (int q = 0; q < 8; ++q) {        // sA = y0[:, s]  (layer-1 input x_t)
      int idx = q * 256 + tid;
      int b = idx >> 8, kf = (idx & 255) * 4;
      *(float4*)&sA[b][kf] =
          *(const float4*)&y0[(size_t)(b * 32 + s) * 1024 + kf];
    }
    __syncthreads();
    const int jb = (int)(blockIdx.x - 256) * 2;
    const int p = wv >> 1, role = wv & 1;
    const int j = jb + p;
    const __bf16* Wm = role ? Wbh1 : Wbi1;
    const __bf16* WR = Wm + (size_t)j * 1024;
    const __bf16* WZ = Wm + (size_t)(1024 + j) * 1024;
    const __bf16* WN = Wm + (size_t)(2048 + j) * 1024;
    float aR[8] = {}, aZ[8] = {}, aN[8] = {};
#pragma unroll
    for (int kk = 0; kk < 4; ++kk) {
      const int k = kk * 256 + lane * 4;
      uint2 uR = *(const uint2*)&WR[k];
      uint2 uZ = *(const uint2*)&WZ[k];
      uint2 uN = *(const uint2*)&WN[k];
      float r0, r1, r2, r3, z0, z1, z2, z3, n0, n1, n2, n3;
      unp2(uR.x, r0, r1); unp2(uR.y, r2, r3);
      unp2(uZ.x, z0, z1); unp2(uZ.y, z2, z3);
      unp2(uN.x, n0, n1); unp2(uN.y, n2, n3);
#pragma unroll
      for (int b = 0; b < 8; ++b) {
        float4 v;
        if (role) {                      // h-side: y1[t-2] direct from L2
          if (s > 0)
            v = *(const float4*)&y1[(size_t)(b * 32 + s - 1) * 1024 + k];
          else
            v = make_float4(0.f, 0.f, 0.f, 0.f);
        } else {
          v = *(const float4*)&sA[b][k];
        }
        aR[b] += v.x * r0 + v.y * r1 + v.z * r2 + v.w * r3;
        aZ[b] += v.x * z0 + v.y * z1 + v.z * z2 + v.w * z3;
        aN[b] += v.x * n0 + v.y * n1 + v.z * n2 + v.w * n3;
      }
    }
#pragma unroll
    for (int d = 1; d < 64; d <<= 1) {
#pragma unroll
      for (int b = 0; b < 8; ++b) {
        aR[b] += __shfl_xor(aR[b], d);
        aZ[b] += __shfl_xor(aZ[b], d);
        aN[b] += __shfl_xor(aN[b], d);
      }
    }
    if (lane == 0) {
#pragma unroll
      for (int b = 0; b < 8; ++b) {
        part[p][role][0][b] = aR[b];
        part[p][role][1][b] = aZ[b];
        part[p][role][2][b] = aN[b];
      }
    }
    __syncthreads();
    if (role == 0 && lane < 8) {
      const int b = lane;
      float xR = part[p][0][0][b], hR = part[p][1][0][b];
      float xZ = part[p][0][1][b], hZ = part[p][1][1][b];
      float xN = part[p][0][2][b], hN = part[p][1][2][b];
      float r = 1.0f / (1.0f + __expf(-(xR + hR + bih1[j] + bhh1[j])));
      float z = 1.0f / (1.0f + __expf(-(xZ + hZ + bih1[1024 + j] + bhh1[1024 + j])));
      float n = tanhf(xN + bih1[2048 + j] + r * (hN + bhh1[2048 + j]));
      float hp = (s > 0) ? y1[(size_t)(b * 32 + s - 1) * 1024 + j] : 0.f;
      y1[(size_t)(b * 32 + s) * 1024 + j] = (1.0f - z) * n + z * hp;
    }
  }
}

// ---------------------------------------------------------------------------
// X0 GEMM: Cp[z][m][n] = sum_{k in chunk z} A[m,k]*B[n,k]
// A: [256, K] bf16.  B: [N, K] fp32.  M-tile 256 (full M), N-tile 128, BK=32,
// 1-deep register prefetch.  SK=16 (proven R7 config).
// ---------------------------------------------------------------------------
__global__ __launch_bounds__(256) void gemm_bt16_k(const __bf16* __restrict__ A,
                                                   const float* __restrict__ Bm,
                                                   float* __restrict__ Cp,
                                                   int N, int K, int ksper) {
  __shared__ __bf16 As[256][40];   // 80B row stride: aligned, ~2-way bank alias
  __shared__ __bf16 Bs[128][40];
  const int tid = threadIdx.x;
  const int bn = blockIdx.x * 128;
  const int lane = tid & 63, wv = tid >> 6;
  const int wr = wv >> 1, wc = wv & 1;
  const int lr = lane & 15, kh = lane >> 4;
  const int brow = tid >> 1, bhalf = tid & 1;
  f32x4 acc[8][4] = {};
  const int kstot = K >> 5;
  int ks0 = blockIdx.z * ksper;
  int ks1 = ks0 + ksper; if (ks1 > kstot) ks1 = kstot;
  uint4 ra0, ra1, ra2, ra3; float4 rb0, rb1, rb2, rb3;
  {
    const int k0 = ks0 << 5;
    const uint4* ap = (const uint4*)(A + (size_t)tid * K + k0);
    ra0 = ap[0]; ra1 = ap[1]; ra2 = ap[2]; ra3 = ap[3];
    const float* bp = Bm + (size_t)(bn + brow) * K + k0 + bhalf * 16;
    rb0 = ((const float4*)bp)[0]; rb1 = ((const float4*)bp)[1];
    rb2 = ((const float4*)bp)[2]; rb3 = ((const float4*)bp)[3];
  }
  for (int ks = ks0; ks < ks1; ++ks) {
    __syncthreads();
    *(uint4*)&As[tid][0]  = ra0;
    *(uint4*)&As[tid][8]  = ra1;
    *(uint4*)&As[tid][16] = ra2;
    *(uint4*)&As[tid][24] = ra3;
    *(bf16x8*)&Bs[brow][bhalf * 16] = cvt8(rb0, rb1);
    *(bf16x8*)&Bs[brow][bhalf * 16 + 8] = cvt8(rb2, rb3);
    __syncthreads();
    if (ks + 1 < ks1) {  // prefetch next K-tile into regs; overlaps with MFMA
      const int k0 = (ks + 1) << 5;
      const uint4* ap = (const uint4*)(A + (size_t)tid * K + k0);
      ra0 = ap[0]; ra1 = ap[1]; ra2 = ap[2]; ra3 = ap[3];
      const float* bp = Bm + (size_t)(bn + brow) * K + k0 + bhalf * 16;
      rb0 = ((const float4*)bp)[0]; rb1 = ((const float4*)bp)[1];
      rb2 = ((const float4*)bp)[2]; rb3 = ((const float4*)bp)[3];
    }
    bf16x8 bfv[4];
#pragma unroll
    for (int ni = 0; ni < 4; ++ni)
      bfv[ni] = *(const bf16x8*)&Bs[wc * 64 + ni * 16 + lr][kh * 8];
#pragma unroll
    for (int mi = 0; mi < 8; ++mi) {
      bf16x8 af = *(const bf16x8*)&As[wr * 128 + mi * 16 + lr][kh * 8];
#pragma unroll
      for (int ni = 0; ni < 4; ++ni)
        acc[mi][ni] = __builtin_amdgcn_mfma_f32_16x16x32_bf16(af, bfv[ni],
                                                              acc[mi][ni], 0, 0, 0);
    }
  }
  float* cp = Cp + (size_t)blockIdx.z * 256 * N;
#pragma unroll
  for (int mi = 0; mi < 8; ++mi) {
#pragma unroll
    for (int ni = 0; ni < 4; ++ni) {
      const int row = wr * 128 + mi * 16 + kh * 4;
      const int col = bn + wc * 64 + ni * 16 + lr;
#pragma unroll
      for (int j = 0; j < 4; ++j)
        cp[(size_t)(row + j) * N + col] = acc[mi][ni][j];
    }
  }
}

// ---------------------------------------------------------------------------
// fp32-input MFMA GEMM (he: B [K,N]) with split-K.
// ---------------------------------------------------------------------------
template <bool BT>
__global__ __launch_bounds__(256) void mfma_gemm_k(const float* __restrict__ A,
                                                   const float* __restrict__ Bm,
                                                   float* __restrict__ Cp,
                                                   int M, int N, int K,
                                                   int lda, int ldb, int ksper) {
  __shared__ __bf16 As[128][40];
  __shared__ __bf16 Bs[128][40];
  const int tid = threadIdx.x;
  const int bm = blockIdx.y * 128, bn = blockIdx.x * 128;
  const int lane = tid & 63, wv = tid >> 6;
  const int wr = wv >> 1, wc = wv & 1;
  const int lr = lane & 15, kh = lane >> 4;
  f32x4 acc[4][4] = {};
  const int kstot = K >> 5;
  int ks0 = blockIdx.z * ksper;
  int ks1 = ks0 + ksper; if (ks1 > kstot) ks1 = kstot;
  for (int ks = ks0; ks < ks1; ++ks) {
    const int k0 = ks << 5;
    __syncthreads();
    {
      const int row = tid >> 1, half = tid & 1;
      const float* ap = A + (size_t)(bm + row) * lda + k0 + half * 16;
      float4 f0 = ((const float4*)ap)[0], f1 = ((const float4*)ap)[1];
      float4 f2 = ((const float4*)ap)[2], f3 = ((const float4*)ap)[3];
      *(bf16x8*)&As[row][half * 16] = cvt8(f0, f1);
      *(bf16x8*)&As[row][half * 16 + 8] = cvt8(f2, f3);
    }
    if (BT) {
      const int row = tid >> 1, half = tid & 1;
      const float* bp = Bm + (size_t)(bn + row) * ldb + k0 + half * 16;
      float4 f0 = ((const float4*)bp)[0], f1 = ((const float4*)bp)[1];
      float4 f2 = ((const float4*)bp)[2], f3 = ((const float4*)bp)[3];
      *(bf16x8*)&Bs[row][half * 16] = cvt8(f0, f1);
      *(bf16x8*)&Bs[row][half * 16 + 8] = cvt8(f2, f3);
    } else {
      const int kk = tid >> 3, ng = tid & 7;
      const float* bp = Bm + (size_t)(k0 + kk) * ldb + bn + ng * 16;
      float4 f[4];
#pragma unroll
      for (int q = 0; q < 4; ++q) f[q] = ((const float4*)bp)[q];
#pragma unroll
      for (int q = 0; q < 4; ++q) {
        Bs[ng * 16 + q * 4 + 0][kk] = (__bf16)f[q].x;
        Bs[ng * 16 + q * 4 + 1][kk] = (__bf16)f[q].y;
        Bs[ng * 16 + q * 4 + 2][kk] = (__bf16)f[q].z;
        Bs[ng * 16 + q * 4 + 3][kk] = (__bf16)f[q].w;
      }
    }
    __syncthreads();
    bf16x8 af[4], bfv[4];
#pragma unroll
    for (int mi = 0; mi < 4; ++mi)
      af[mi] = *(const bf16x8*)&As[wr * 64 + mi * 16 + lr][kh * 8];
#pragma unroll
    for (int ni = 0; ni < 4; ++ni)
      bfv[ni] = *(const bf16x8*)&Bs[wc * 64 + ni * 16 + lr][kh * 8];
#pragma unroll
    for (int mi = 0; mi < 4; ++mi)
#pragma unroll
      for (int ni = 0; ni < 4; ++ni)
        acc[mi][ni] = __builtin_amdgcn_mfma_f32_16x16x32_bf16(af[mi], bfv[ni],
                                                              acc[mi][ni], 0, 0, 0);
  }
  float* cp = Cp + (size_t)blockIdx.z * M * N;
#pragma unroll
  for (int mi = 0; mi < 4; ++mi) {
#pragma unroll
    for (int ni = 0; ni < 4; ++ni) {
      const int row = bm + wr * 64 + mi * 16 + kh * 4;
      const int col = bn + wc * 64 + ni * 16 + lr;
#pragma unroll
      for (int j = 0; j < 4; ++j)
        cp[(size_t)(row + j) * N + col] = acc[mi][ni][j];
    }
  }
}

// C[i] = bias[i%N] + sum_sk Cp[sk][i]
__global__ __launch_bounds__(256) void reduce_k(const float* __restrict__ Cp,
                                                const float* __restrict__ bias,
                                                float* __restrict__ C,
                                                int MN, int N, int nsk) {
  int i = (blockIdx.x * 256 + threadIdx.x) * 4;
  if (i >= MN) return;
  float4 s = make_float4(0.f, 0.f, 0.f, 0.f);
  if (bias) s = *(const float4*)&bias[i % N];
  for (int sk = 0; sk < nsk; ++sk) {
    float4 p = *(const float4*)&Cp[(size_t)sk * MN + i];
    s.x += p.x; s.y += p.y; s.z += p.z; s.w += p.w;
  }
  *(float4*)&C[i] = s;
}

// ---------------------------------------------------------------------------
// h[g,n,c] = he[g,c] + sum_f x_node[g,n,f] * Wg[f,c]   -> stored bf16
// ---------------------------------------------------------------------------
__global__ __launch_bounds__(256) void node_h_k(const float* __restrict__ xn,
                                                const float* __restrict__ Wg,
                                                const float* __restrict__ he,
                                                bf16* __restrict__ hbuf) {
  __shared__ float xns[64][32];
  __shared__ float wgs[32][256];
  const int cq = blockIdx.x, g = blockIdx.y;
  const int tid = threadIdx.x;
  for (int idx = tid; idx < 2048; idx += 256) xns[idx >> 5][idx & 31] = xn[g * 2048 + idx];
  for (int r = 0; r < 32; ++r) wgs[r][tid] = Wg[r * 1024 + cq * 256 + tid];
  __syncthreads();
  const float hev = he[g * 1024 + cq * 256 + tid];
  for (int n0 = 0; n0 < 64; n0 += 8) {
    float acc[8];
#pragma unroll
    for (int nn = 0; nn < 8; ++nn) acc[nn] = hev;
    for (int f = 0; f < 32; ++f) {
      float w = wgs[f][tid];
#pragma unroll
      for (int nn = 0; nn < 8; ++nn) acc[nn] += xns[n0 + nn][f] * w;
    }
#pragma unroll
    for (int nn = 0; nn < 8; ++nn)
      hbuf[(size_t)(g * 64 + n0 + nn) * 1024 + cq * 256 + tid] = __float2bfloat16(acc[nn]);
  }
}

// ---------------------------------------------------------------------------
// a_s[row,hd] = sum_e h[row, hd*256+e] * att_src[hd,e]; same for a_d.
// ---------------------------------------------------------------------------
__global__ __launch_bounds__(256) void as_ad_k(const bf16* __restrict__ hbuf,
                                               const float* __restrict__ att_s,
                                               const float* __restrict__ att_d,
                                               float* __restrict__ as_o,
                                               float* __restrict__ ad_o) {
  const int tid = threadIdx.x;
  const int lane = tid & 63, wv = tid >> 6;
  const int row = blockIdx.x * 4 + wv;
  const int hd = lane >> 4;
  const int e0 = (lane & 15) * 16;
  float as_r[16], ad_r[16];
#pragma unroll
  for (int q = 0; q < 4; ++q) {
    float4 v = *(const float4*)(att_s + hd * 256 + e0 + q * 4);
    as_r[q * 4 + 0] = v.x; as_r[q * 4 + 1] = v.y; as_r[q * 4 + 2] = v.z; as_r[q * 4 + 3] = v.w;
    float4 w = *(const float4*)(att_d + hd * 256 + e0 + q * 4);
    ad_r[q * 4 + 0] = w.x; ad_r[q * 4 + 1] = w.y; ad_r[q * 4 + 2] = w.z; ad_r[q * 4 + 3] = w.w;
  }
  const uint4* hp = (const uint4*)(hbuf + (size_t)row * 1024 + lane * 16);
  uint4 p0 = hp[0], p1 = hp[1];
  float hv[16];
  unp2(p0.x, hv[0], hv[1]);  unp2(p0.y, hv[2], hv[3]);
  unp2(p0.z, hv[4], hv[5]);  unp2(p0.w, hv[6], hv[7]);
  unp2(p1.x, hv[8], hv[9]);  unp2(p1.y, hv[10], hv[11]);
  unp2(p1.z, hv[12], hv[13]); unp2(p1.w, hv[14], hv[15]);
  float ps = 0.f, pd = 0.f;
#pragma unroll
  for (int i = 0; i < 16; ++i) { ps += as_r[i] * hv[i]; pd += ad_r[i] * hv[i]; }
#pragma unroll
  for (int m = 1; m < 16; m <<= 1) { ps += __shfl_xor(ps, m); pd += __shfl_xor(pd, m); }
  if ((lane & 15) == 0) { as_o[row * 4 + hd] = ps; ad_o[row * 4 + hd] = pd; }
}

// ---------------------------------------------------------------------------
// Per graph g: softmax over sources + head-mean aggregation + bias + relu.
// ---------------------------------------------------------------------------
__global__ __launch_bounds__(256) void attn_agg_k(const bf16* __restrict__ hbuf,
                                                  const float* __restrict__ as_i,
                                                  const float* __restrict__ ad_i,
                                                  const float* __restrict__ bgat,
                                                  __bf16* __restrict__ seq) {
  __shared__ float ass[256], ads[256], bgs[256];
  __shared__ float alpha[4][64][64];   // [hd][j][i]
  __shared__ float hq[64][260];        // one head-quarter of h, fp32
  const int g = blockIdx.x, tid = threadIdx.x;
  ass[tid] = as_i[g * 256 + tid];
  ads[tid] = ad_i[g * 256 + tid];
  bgs[tid] = bgat[tid];
  __syncthreads();
  {
    const int hd = tid >> 6, i = tid & 63;
    const float ad = ads[i * 4 + hd];
    float m = -1e30f;
    for (int j = 0; j < 64; ++j) {
      float s = ad + ass[j * 4 + hd];
      s = s > 0.0f ? s : 0.2f * s;
      m = fmaxf(m, s);
    }
    float sum = 0.0f;
    for (int j = 0; j < 64; ++j) {
      float s = ad + ass[j * 4 + hd];
      s = s > 0.0f ? s : 0.2f * s;
      sum += __expf(s - m);
    }
    const float inv = 1.0f / sum;
    for (int j = 0; j < 64; ++j) {
      float s = ad + ass[j * 4 + hd];
      s = s > 0.0f ? s : 0.2f * s;
      alpha[hd][j][i] = __expf(s - m) * inv;
    }
  }
  const int i = tid & 63, eq = tid >> 6;
  float acc[64] = {};
  for (int hd = 0; hd < 4; ++hd) {
    __syncthreads();
    for (int idx = tid; idx < 2048; idx += 256) {
      int j = idx >> 5, ch = idx & 31;
      uint4 p = *(const uint4*)(hbuf + (size_t)(g * 64 + j) * 1024 + hd * 256 + ch * 8);
      float f0, f1, f2, f3, f4, f5, f6, f7;
      unp2(p.x, f0, f1); unp2(p.y, f2, f3); unp2(p.z, f4, f5); unp2(p.w, f6, f7);
      *(float4*)&hq[j][ch * 8] = make_float4(f0, f1, f2, f3);
      *(float4*)&hq[j][ch * 8 + 4] = make_float4(f4, f5, f6, f7);
    }
    __syncthreads();
    for (int j = 0; j < 64; ++j) {
      const float a = alpha[hd][j][i];
      const float* hr = &hq[j][eq * 64];
#pragma unroll
      for (int q = 0; q < 16; ++q) {
        float4 hv = *(const float4*)(hr + q * 4);
        acc[q * 4 + 0] += a * hv.x; acc[q * 4 + 1] += a * hv.y;
        acc[q * 4 + 2] += a * hv.z; acc[q * 4 + 3] += a * hv.w;
      }
    }
  }
  __bf16* op = seq + (size_t)g * 16384 + i * 256 + eq * 64;
#pragma unroll
  for (int q = 0; q < 8; ++q) {
    float4 lo, hi;
    lo.x = fmaxf(bgs[eq * 64 + q * 8 + 0] + 0.25f * acc[q * 8 + 0], 0.0f);
    lo.y = fmaxf(bgs[eq * 64 + q * 8 + 1] + 0.25f * acc[q * 8 + 1], 0.0f);
    lo.z = fmaxf(bgs[eq * 64 + q * 8 + 2] + 0.25f * acc[q * 8 + 2], 0.0f);
    lo.w = fmaxf(bgs[eq * 64 + q * 8 + 3] + 0.25f * acc[q * 8 + 3], 0.0f);
    hi.x = fmaxf(bgs[eq * 64 + q * 8 + 4] + 0.25f * acc[q * 8 + 4], 0.0f);
    hi.y = fmaxf(bgs[eq * 64 + q * 8 + 5] + 0.25f * acc[q * 8 + 5], 0.0f);
    hi.z = fmaxf(bgs[eq * 64 + q * 8 + 6] + 0.25f * acc[q * 8 + 6], 0.0f);
    hi.w = fmaxf(bgs[eq * 64 + q * 8 + 7] + 0.25f * acc[q * 8 + 7], 0.0f);
    *(bf16x8*)(op + q * 8) = cvt8(lo, hi);
  }
}

// ---------------------------------------------------------------------------
// out[b,o] = b_fc[o] + sum_k y1[b,31,k] * Wfc[k,o]
// ---------------------------------------------------------------------------
__global__ __launch_bounds__(256) void fc_k(const float* __restrict__ y1,
                                            const float* __restrict__ Wfc,
                                            const float* __restrict__ bfc,
                                            float* __restrict__ out) {
  __shared__ float As[8][1024];
  const int tid = threadIdx.x;
  for (int idx = tid; idx < 8192; idx += 256) {
    int b = idx >> 10, k = idx & 1023;
    As[b][k] = y1[(size_t)(b * 32 + 31) * 1024 + k];
  }
  __syncthreads();
  const int ol = tid >> 2, kq = tid & 3;
  const int o = blockIdx.x * 64 + ol;
  float acc[8] = {};
  if (o < 2016) {
    for (int i2 = 0; i2 < 256; ++i2) {
      int k = i2 * 4 + kq;
      float w = Wfc[(size_t)k * 2016 + o];
#pragma unroll
      for (int b = 0; b < 8; ++b) acc[b] += As[b][k] * w;
    }
  }
#pragma unroll
  for (int b = 0; b < 8; ++b) {
    acc[b] += __shfl_xor(acc[b], 1);
    acc[b] += __shfl_xor(acc[b], 2);
  }
  if (kq == 0 && o < 2016) {
#pragma unroll
    for (int b = 0; b < 8; ++b) out[b * 2016 + o] = acc[b] + bfc[o];
  }
}

// ---------------------------------------------------------------------------
extern "C" void kernel_launch(void* const* d_in, const int* in_sizes, int n_in,
                              void* d_out, int out_size, void* d_ws, size_t ws_size,
                              hipStream_t stream) {
  (void)in_sizes; (void)n_in; (void)out_size; (void)ws_size;
  const float* x_node = (const float*)d_in[0];
  const float* x_edge = (const float*)d_in[1];
  // d_in[2] = edge_index: complete graph + self loops -> dense; unused.
  const float* W_gat = (const float*)d_in[3];
  const float* att_s = (const float*)d_in[4];
  const float* att_d = (const float*)d_in[5];
  const float* b_gat = (const float*)d_in[6];
  const float* W_ih0 = (const float*)d_in[7];
  const float* W_hh0 = (const float*)d_in[8];
  const float* b_ih0 = (const float*)d_in[9];
  const float* b_hh0 = (const float*)d_in[10];
  const float* W_ih1 = (const float*)d_in[11];
  const float* W_hh1 = (const float*)d_in[12];
  const float* b_ih1 = (const float*)d_in[13];
  const float* b_hh1 = (const float*)d_in[14];
  const float* W_fc  = (const float*)d_in[15];
  const float* b_fc  = (const float*)d_in[16];

  char* ws = (char*)d_ws;
  size_t off = 0;
  float*  he   = (float*)(ws + off);   off += 256u * 1024 * 4;          // 1 MB
  float*  a_s  = (float*)(ws + off);   off += 256u * 64 * 4 * 4;        // 256 KB
  float*  a_d  = (float*)(ws + off);   off += 256u * 64 * 4 * 4;        // 256 KB
  bf16*   hb   = (bf16*)(ws + off);    off += 256u * 64 * 1024 * 2;     // 32 MB
  __bf16* seq  = (__bf16*)(ws + off);  off += 256u * 16384 * 2;         // 8 MB
  float*  X0   = (float*)(ws + off);   off += 256u * 3072 * 4;          // 3 MB
  float*  y0   = (float*)(ws + off);   off += 256u * 1024 * 4;          // 1 MB
  float*  y1   = (float*)(ws + off);   off += 256u * 1024 * 4;          // 1 MB
  __bf16* Wb0  = (__bf16*)(ws + off);  off += 3072u * 1024 * 2;         // 6 MB
  __bf16* Wbi1 = (__bf16*)(ws + off);  off += 3072u * 1024 * 2;         // 6 MB
  __bf16* Wbh1 = (__bf16*)(ws + off);  off += 3072u * 1024 * 2;         // 6 MB
  off = (off + 255) & ~(size_t)255;
  float*  Cp   = (float*)(ws + off);   off += (size_t)16 * 256 * 3072 * 4; // 48 MB

  // 0) bf16 copies of RNN weights (once per call; L2-resident thereafter)
  wcvt_k<<<1536, 256, 0, stream>>>(W_hh0, W_ih1, W_hh1, Wb0, Wbi1, Wbh1);
  // 1) he = x_edge @ W_gat[32:, :]   (M=256, N=1024, K=2016, B is [K,N]) SK=8
  mfma_gemm_k<false><<<dim3(8, 2, 8), 256, 0, stream>>>(
      x_edge, W_gat + 32 * 1024, Cp, 256, 1024, 2016, 2016, 1024, 8);
  reduce_k<<<256, 256, 0, stream>>>(Cp, nullptr, he, 256 * 1024, 1024, 8);
  // 2) h = node-proj + he (bf16)
  node_h_k<<<dim3(4, 256), 256, 0, stream>>>(x_node, W_gat, he, hb);
  // 3) attention logits
  as_ad_k<<<4096, 256, 0, stream>>>(hb, att_s, att_d, a_s, a_d);
  // 4) softmax + aggregation + relu -> seq [256, 16384] bf16
  attn_agg_k<<<256, 256, 0, stream>>>(hb, a_s, a_d, b_gat, seq);
  // 5) X0 = seq @ W_ih0^T + b_ih0   (M=256 full-tile, N=3072, K=16384) SK=16
  gemm_bt16_k<<<dim3(24, 1, 16), 256, 0, stream>>>(seq, W_ih0, Cp,
                                                   3072, 16384, 32);
  reduce_k<<<768, 256, 0, stream>>>(Cp, b_ih0, X0, 256 * 3072, 3072, 16);
  // 6) Both GRU layers, software-pipelined: launch t = layer0 step t (256
  //    blocks) + layer1 step t-1 (512 blocks, fused fp32 input projection).
  for (int t = 0; t <= 32; ++t)
    gru_fused2_k<<<768, 256, 0, stream>>>(X0, Wb0, b_hh0, y0,
                                          Wbi1, b_ih1, Wbh1, b_hh1, y1, t);
  // 7) out = y1[:, 31] @ W_fc + b_fc
  fc_k<<<32, 256, 0, stream>>>(y1, W_fc, b_fc, (float*)d_out);
}